// Round 7
// baseline (3645.937 us; speedup 1.0000x reference)
//
#include <hip/hip_runtime.h>
#include <hip/hip_cooperative_groups.h>
#include <stdint.h>

namespace cg = cooperative_groups;

#define NB 2048
#define NW 6
#define ND 1024
#define NH 8
#define NDH 128
#define NDP 1028          // padded LDS row stride (floats)
#define NTOT 12582912u
#define BT 256            // threads per block (4 waves)
#define NGRID 512         // 2 blocks/CU * 256 CU
#define BPB 4             // batch elements per block (coop path)
#define C_DT 0.09f
#define C_COUP 0.01f
#define C_TOL 0.05f
#define C_THIGH 0.22f
#define NSTEPS 16

typedef __attribute__((ext_vector_type(8))) short short8v;   // 8 bf16 (4 VGPR)
typedef __attribute__((ext_vector_type(4))) float f32x4;     // MFMA acc

struct Flags {           // fallback (per-step) control
  int done; int apply_noise; int cnt_low; int cnt_high; int arrived;
  float sum_T;
};
struct Ctrl {            // cooperative control (per-step slots, no resets)
  int arrived;           // monotonic across steps
  int done[NSTEPS];
  int apply[NSTEPS];
  int cnt_low[NSTEPS];
  int cnt_high[NSTEPS];
  float sum_T[NSTEPS];
};

__host__ __device__ __forceinline__ uint32_t rotl32(uint32_t x, uint32_t d) {
  return (x << d) | (x >> (32u - d));
}

// JAX threefry2x32 (20 rounds), matches jax/_src/prng.py
__host__ __device__ __forceinline__ void tf2x32(uint32_t k0, uint32_t k1,
                                                uint32_t x0, uint32_t x1,
                                                uint32_t& o0, uint32_t& o1) {
  const uint32_t k2 = k0 ^ k1 ^ 0x1BD11BDAu;
#define TF_R4(a,b,c,d) \
  x0 += x1; x1 = rotl32(x1,a); x1 ^= x0; \
  x0 += x1; x1 = rotl32(x1,b); x1 ^= x0; \
  x0 += x1; x1 = rotl32(x1,c); x1 ^= x0; \
  x0 += x1; x1 = rotl32(x1,d); x1 ^= x0;
  x0 += k0; x1 += k1;
  TF_R4(13u,15u,26u,6u)  x0 += k1; x1 += k2 + 1u;
  TF_R4(17u,29u,16u,24u) x0 += k2; x1 += k0 + 2u;
  TF_R4(13u,15u,26u,6u)  x0 += k0; x1 += k1 + 3u;
  TF_R4(17u,29u,16u,24u) x0 += k1; x1 += k2 + 4u;
  TF_R4(13u,15u,26u,6u)  x0 += k2; x1 += k0 + 5u;
#undef TF_R4
  o0 = x0; o1 = x1;
}

// XLA ErfInv32 (Giles) polynomial — matches xla/client/lib/math.cc
__device__ __forceinline__ float erfinv_xla(float x) {
  const float w = -log1pf(-x * x);
  float ps, pb;
  const float ws = w - 2.5f;
  ps = 2.81022636e-08f;
  ps = fmaf(ps, ws, 3.43273939e-07f);
  ps = fmaf(ps, ws, -3.5233877e-06f);
  ps = fmaf(ps, ws, -4.39150654e-06f);
  ps = fmaf(ps, ws, 0.00021858087f);
  ps = fmaf(ps, ws, -0.00125372503f);
  ps = fmaf(ps, ws, -0.00417768164f);
  ps = fmaf(ps, ws, 0.246640727f);
  ps = fmaf(ps, ws, 1.50140941f);
  const float wb = sqrtf(w) - 3.0f;
  pb = -0.000200214257f;
  pb = fmaf(pb, wb, 0.000100950558f);
  pb = fmaf(pb, wb, 0.00134934322f);
  pb = fmaf(pb, wb, -0.00367342844f);
  pb = fmaf(pb, wb, 0.00573950773f);
  pb = fmaf(pb, wb, -0.0076224613f);
  pb = fmaf(pb, wb, 0.00943887047f);
  pb = fmaf(pb, wb, 1.00167406f);
  pb = fmaf(pb, wb, 2.83297682f);
  const float p = (w < 5.0f) ? ps : pb;
  return p * x;
}

__device__ __forceinline__ float noise_z(uint32_t k0, uint32_t k1, uint32_t p) {
  // JAX threefry_partitionable: counter (hi=0, lo=p), bits = o0 ^ o1
  uint32_t o0, o1;
  tf2x32(k0, k1, 0u, p, o0, o1);
  const uint32_t bits = o0 ^ o1;
  const float f = __uint_as_float((bits >> 9) | 0x3F800000u) - 1.0f;
  const float lo = -0.99999994f;                 // nextafter(-1,0) in f32
  const float u = fmaxf(lo, fmaf(f, 2.0f, lo));
  return 1.41421356237f * erfinv_xla(u);
}

// f32 -> bf16 round-to-nearest-even
__device__ __forceinline__ unsigned short f2bf(float f) {
  const uint32_t u = __float_as_uint(f);
  return (unsigned short)((u + 0x7FFFu + ((u >> 16) & 1u)) >> 16);
}
__device__ __forceinline__ float bf2f(unsigned short h) {
  return __uint_as_float(((uint32_t)h) << 16);
}

// Batched 6-value block reduction for BT=256 (4 waves): 36 shuffles, 2 syncs.
__device__ __forceinline__ void block_sum6(float p[NW], float* red /*[4*NW]*/) {
  #pragma unroll
  for (int w = 0; w < NW; ++w)
    #pragma unroll
    for (int off = 32; off > 0; off >>= 1) p[w] += __shfl_down(p[w], off, 64);
  const int t = threadIdx.x;
  __syncthreads();                       // protect red from previous use
  if ((t & 63) == 0) {
    #pragma unroll
    for (int w = 0; w < NW; ++w) red[(t >> 6) * NW + w] = p[w];
  }
  __syncthreads();
  #pragma unroll
  for (int w = 0; w < NW; ++w)
    p[w] = red[w] + red[NW + w] + red[2 * NW + w] + red[3 * NW + w];
}

// single-value block reduce for 256-thread trailing noise kernel
__device__ __forceinline__ float block_sum4(float v, float* red) {
  #pragma unroll
  for (int off = 32; off > 0; off >>= 1) v += __shfl_down(v, off, 64);
  const int t = threadIdx.x;
  __syncthreads();
  if ((t & 63) == 0) red[t >> 6] = v;
  __syncthreads();
  return red[0] + red[1] + red[2] + red[3];
}

__global__ void init_kernel(Flags* f, Ctrl* c, float* curve) {
  const int t = threadIdx.x;
  if (t == 0) {
    f->done = 0; f->apply_noise = 0;
    f->cnt_low = 0; f->cnt_high = 0; f->arrived = 0; f->sum_T = 0.0f;
    c->arrived = 0;
  }
  if (t < NSTEPS) {
    c->done[t] = 0; c->apply[t] = 0;
    c->cnt_low[t] = 0; c->cnt_high[t] = 0; c->sum_T[t] = 0.0f;
    curve[t] = __int_as_float(0x7FC00000);   // NaN
  }
}

// M[h][d][e] = sum_r U[h][d][r] * V[h][r][e], bf16 hi/lo in B-fragment order:
// frag = ((h*8 + nt)*4 + ks)*64 + lane, 8 bf16 each;
// lane = (e&15) | ((d>>3)&3)<<4, j = d&7, nt = e>>4, ks = d>>5.
__global__ __launch_bounds__(128) void precompute_M(const float* __restrict__ U,
                                                    const float* __restrict__ V,
                                                    unsigned short* __restrict__ Mhi,
                                                    unsigned short* __restrict__ Mlo) {
  const int hd = blockIdx.x;          // h*128 + d
  const int h = hd >> 7;
  const int d = hd & 127;
  const int e = threadIdx.x;
  __shared__ float u[64];
  if (e < 64) u[e] = U[hd * 64 + e];
  __syncthreads();
  float acc = 0.0f;
  #pragma unroll
  for (int r = 0; r < 64; ++r)
    acc = fmaf(u[r], V[(h * 64 + r) * 128 + e], acc);
  const unsigned short hi = f2bf(acc);
  const unsigned short lo = f2bf(acc - bf2f(hi));
  const int nt = e >> 4, ks = d >> 5;
  const int lane = (e & 15) | (((d >> 3) & 3) << 4);
  const int j = d & 7;
  const size_t idx = ((((size_t)(h * 8 + nt)) * 4 + ks) * 64 + lane) * 8 + j;
  Mhi[idx] = hi; Mlo[idx] = lo;
}

// ===================== cooperative (persistent) path =====================
__global__ __launch_bounds__(BT, 2) void dyn_kernel(
    const float* __restrict__ S0, float* __restrict__ outS,
    const float* __restrict__ signal,
    const unsigned short* __restrict__ Mhi, const unsigned short* __restrict__ Mlo,
    Ctrl* __restrict__ ctrl, float* __restrict__ curve) {
  cg::grid_group grid = cg::this_grid();
  __shared__ __align__(16) float xs2[2][NW][NDP];   // 48.2 KB: x, then drift (in-place)
  __shared__ __align__(16) float mh2[2][NW][NDH];   // 6 KB
  __shared__ float red[4 * NW];
  __shared__ int bc[2];
  const int t = threadIdx.x;
  const int g = blockIdx.x;
  const int e0 = t << 2;              // 4 cols per thread (elementwise phases)

  // persistent state: 4 batch elements, 24 f32 each per thread (96 VGPR)
  float S[BPB][NW][4];
  #pragma unroll
  for (int i = 0; i < BPB; ++i) {
    const int b = g * BPB + i;
    #pragma unroll
    for (int w = 0; w < NW; ++w) {
      const float4 a = *reinterpret_cast<const float4*>(
          S0 + (size_t)(b * NW + w) * ND + e0);
      S[i][w][0]=a.x; S[i][w][1]=a.y; S[i][w][2]=a.z; S[i][w][3]=a.w;
    }
  }
  float Tb[BPB];                      // only thread 0's copy is meaningful

  int broke = 0;
  for (int k = 0; k < NSTEPS; ++k) {
    if (k > 0) {
      if (t == 0) {
        bc[0] = atomicAdd(&ctrl->done[k - 1], 0);
        bc[1] = atomicAdd(&ctrl->apply[k - 1], 0);
      }
      __syncthreads();
      const int done_prev = bc[0];
      const int appl = bc[1];
      if (done_prev) { broke = 1; break; }
      if (appl) {   // pending noise of step k-1, in registers
        uint32_t nk0, nk1; tf2x32(0u, 1u, 0u, (uint32_t)(k - 1), nk0, nk1);
        #pragma unroll
        for (int i = 0; i < BPB; ++i) {
          const uint32_t bb = (uint32_t)(g * BPB + i);
          float p[NW];
          #pragma unroll
          for (int w = 0; w < NW; ++w) {
            const uint32_t rowbase = (bb * NW + (uint32_t)w) * ND + (uint32_t)e0;
            #pragma unroll
            for (int j = 0; j < 4; ++j)
              S[i][w][j] = fmaf(0.01f, noise_z(nk0, nk1, rowbase + (uint32_t)j),
                                S[i][w][j]);
            p[w] = S[i][w][0]*S[i][w][0] + S[i][w][1]*S[i][w][1] +
                   S[i][w][2]*S[i][w][2] + S[i][w][3]*S[i][w][3];
          }
          block_sum6(p, red);
          #pragma unroll
          for (int w = 0; w < NW; ++w) {
            const float inv = 1.0f / (sqrtf(p[w]) + 1e-8f);
            #pragma unroll
            for (int j = 0; j < 4; ++j) S[i][w][j] *= inv;
          }
        }
      }
    }

    // ---- two MFMA passes, 2 batch elements each (rows 0-5 / 8-13) ----
    #pragma unroll
    for (int ps = 0; ps < 2; ++ps) {
      #pragma unroll
      for (int i = 0; i < 2; ++i) {
        #pragma unroll
        for (int w = 0; w < NW; ++w) {
          float4 a;
          a.x = S[ps*2+i][w][0]; a.y = S[ps*2+i][w][1];
          a.z = S[ps*2+i][w][2]; a.w = S[ps*2+i][w][3];
          *reinterpret_cast<float4*>(&xs2[i][w][e0]) = a;
        }
      }
      __syncthreads();
      for (int idx = t; idx < 2 * NW * NDH; idx += BT) {   // 6 iters
        const int i = idx / (NW * NDH);
        const int r = idx - i * (NW * NDH);
        const int w = r >> 7, el = r & 127;
        float s = 0.0f;
        #pragma unroll
        for (int hh = 0; hh < NH; ++hh) s += xs2[i][w][hh * NDH + el];
        mh2[i][w][el] = s * 0.125f;
      }
      __syncthreads();
      {
        const int l = t & 63, wv = t >> 6;
        const int arow = l & 15, kg = l >> 4;
        const int ai = arow >> 3, ar = arow & 7;
        #pragma unroll 1
        for (int h2 = 0; h2 < 2; ++h2) {
          const int hh = wv * 2 + h2;
          f32x4 acc0,acc1,acc2,acc3,acc4,acc5,acc6,acc7;
          acc0=acc1=acc2=acc3=acc4=acc5=acc6=acc7=(f32x4){0.f,0.f,0.f,0.f};
          f32x4* accp[8] = {&acc0,&acc1,&acc2,&acc3,&acc4,&acc5,&acc6,&acc7};
          #pragma unroll
          for (int ks = 0; ks < 4; ++ks) {
            short8v ahi = (short8v)0, alo = (short8v)0;
            if (ar < NW) {
              const float* xp = &xs2[ai][ar][hh * NDH + ks * 32 + kg * 8];
              const float4 xa = *reinterpret_cast<const float4*>(xp);
              const float4 xb = *reinterpret_cast<const float4*>(xp + 4);
              const float xf[8] = {xa.x,xa.y,xa.z,xa.w,xb.x,xb.y,xb.z,xb.w};
              #pragma unroll
              for (int j = 0; j < 8; ++j) {
                const unsigned short hi = f2bf(xf[j]);
                ahi[j] = (short)hi;
                alo[j] = (short)f2bf(xf[j] - bf2f(hi));
              }
            }
            #pragma unroll
            for (int nt = 0; nt < 8; ++nt) {
              const size_t fo = ((((size_t)(hh * 8 + nt)) * 4 + ks) * 64 + l) * 8;
              const short8v bhi = *reinterpret_cast<const short8v*>(Mhi + fo);
              const short8v blo = *reinterpret_cast<const short8v*>(Mlo + fo);
              f32x4 a = *accp[nt];
              a = __builtin_amdgcn_mfma_f32_16x16x32_bf16(alo, bhi, a, 0, 0, 0);
              a = __builtin_amdgcn_mfma_f32_16x16x32_bf16(ahi, blo, a, 0, 0, 0);
              a = __builtin_amdgcn_mfma_f32_16x16x32_bf16(ahi, bhi, a, 0, 0, 0);
              *accp[nt] = a;
            }
          }
          #pragma unroll
          for (int nt = 0; nt < 8; ++nt) {
            const f32x4 a = *accp[nt];
            #pragma unroll
            for (int r = 0; r < 4; ++r) {
              const int row = kg * 4 + r;
              const int ci = row >> 3, cr = row & 7;
              if (cr < NW) xs2[ci][cr][hh * NDH + nt * 16 + arow] = a[r];
            }
          }
        }
      }
      __syncthreads();
      #pragma unroll
      for (int i = 0; i < 2; ++i) {
        const int ib = ps * 2 + i;
        const int b = g * BPB + ib;
        float acc[NW][4];
        float p[NW];
        #pragma unroll
        for (int w = 0; w < NW; ++w) {
          const float4 sg = *reinterpret_cast<const float4*>(
              signal + (size_t)(b * NW + w) * ND + e0);
          const float4 dv = *reinterpret_cast<const float4*>(&xs2[i][w][e0]);
          const float4 hh = *reinterpret_cast<const float4*>(&mh2[i][w][e0 & 127]);
          const float sgf[4] = {sg.x, sg.y, sg.z, sg.w};
          const float dvf[4] = {dv.x, dv.y, dv.z, dv.w};
          const float mhf[4] = {hh.x, hh.y, hh.z, hh.w};
          float s2 = 0.0f;
          #pragma unroll
          for (int j = 0; j < 4; ++j) {
            const float out = -dvf[j] + C_COUP * (mhf[j] - S[ib][w][j]) + sgf[j];
            acc[w][j] = fmaf(C_DT, out, S[ib][w][j]);
            s2 = fmaf(acc[w][j], acc[w][j], s2);
          }
          p[w] = s2;
        }
        block_sum6(p, red);
        #pragma unroll
        for (int w = 0; w < NW; ++w) {
          const float n = sqrtf(p[w]);
          const float scale = fminf(fmaxf(n, 1e-3f), 12.0f) / fmaxf(n, 1e-8f);
          const float inv_norm = 1.0f / (n * scale + 1e-12f);
          #pragma unroll
          for (int j = 0; j < 4; ++j) {
            const float o = acc[w][j] * scale;
            S[ib][w][j] = o;                 // new state
            acc[w][j] = o * inv_norm;        // normed, for tension
          }
        }
        float pc[NW];
        #pragma unroll
        for (int w = 0; w < NW; ++w) pc[w] = 0.0f;
        #pragma unroll
        for (int j = 0; j < 4; ++j) {
          float md = 0.0f;
          #pragma unroll
          for (int w = 0; w < NW; ++w) md += acc[w][j];
          md *= (1.0f / 6.0f);
          #pragma unroll
          for (int w = 0; w < NW; ++w) pc[w] = fmaf(acc[w][j], md, pc[w]);
        }
        block_sum6(pc, red);
        if (t == 0)
          Tb[ib] = 1.0f - (pc[0]+pc[1]+pc[2]+pc[3]+pc[4]+pc[5]) * (1.0f / 6.0f);
      }
    }  // passes

    if (t == 0) {
      float st = 0.0f; int cl = 0, ch = 0;
      #pragma unroll
      for (int i = 0; i < BPB; ++i) {
        st += Tb[i];
        cl += (Tb[i] < C_TOL) ? 1 : 0;
        ch += (Tb[i] > C_THIGH) ? 1 : 0;
      }
      atomicAdd(&ctrl->sum_T[k], st);
      if (cl) atomicAdd(&ctrl->cnt_low[k], cl);
      if (ch) atomicAdd(&ctrl->cnt_high[k], ch);
      __threadfence();
      const int ticket = atomicAdd(&ctrl->arrived, 1);
      if (ticket == (k + 1) * NGRID - 1) {
        const float sT = atomicAdd(&ctrl->sum_T[k], 0.0f);
        const int cln = atomicAdd(&ctrl->cnt_low[k], 0);
        const int chn = atomicAdd(&ctrl->cnt_high[k], 0);
        curve[k] = sT * (1.0f / 2048.0f);
        const int nd = (cln == NB) ? 1 : 0;
        atomicExch(&ctrl->done[k], nd);
        atomicExch(&ctrl->apply[k], (!nd && chn > 0) ? 1 : 0);
        __threadfence();
      }
    }
    grid.sync();
  }  // steps

  if (!broke) {   // trailing pending noise of the final executed step
    if (t == 0) bc[0] = atomicAdd(&ctrl->apply[NSTEPS - 1], 0);
    __syncthreads();
    if (bc[0]) {
      uint32_t nk0, nk1; tf2x32(0u, 1u, 0u, (uint32_t)(NSTEPS - 1), nk0, nk1);
      #pragma unroll
      for (int i = 0; i < BPB; ++i) {
        const uint32_t bb = (uint32_t)(g * BPB + i);
        float p[NW];
        #pragma unroll
        for (int w = 0; w < NW; ++w) {
          const uint32_t rowbase = (bb * NW + (uint32_t)w) * ND + (uint32_t)e0;
          #pragma unroll
          for (int j = 0; j < 4; ++j)
            S[i][w][j] = fmaf(0.01f, noise_z(nk0, nk1, rowbase + (uint32_t)j),
                              S[i][w][j]);
          p[w] = S[i][w][0]*S[i][w][0] + S[i][w][1]*S[i][w][1] +
                 S[i][w][2]*S[i][w][2] + S[i][w][3]*S[i][w][3];
        }
        block_sum6(p, red);
        #pragma unroll
        for (int w = 0; w < NW; ++w) {
          const float inv = 1.0f / (sqrtf(p[w]) + 1e-8f);
          #pragma unroll
          for (int j = 0; j < 4; ++j) S[i][w][j] *= inv;
        }
      }
    }
  }

  #pragma unroll
  for (int i = 0; i < BPB; ++i) {
    const int b = g * BPB + i;
    #pragma unroll
    for (int w = 0; w < NW; ++w) {
      float4 a;
      a.x = S[i][w][0]; a.y = S[i][w][1]; a.z = S[i][w][2]; a.w = S[i][w][3];
      *reinterpret_cast<float4*>(outS + (size_t)(b * NW + w) * ND + e0) = a;
    }
  }
}

// ===================== fallback (per-step) path — round-5, proven ==========
__global__ __launch_bounds__(BT, 3) void step_kernel(
    const float* __restrict__ Sin, float* __restrict__ Sout,
    const float* __restrict__ signal,
    const unsigned short* __restrict__ Mhi, const unsigned short* __restrict__ Mlo,
    Flags* __restrict__ flags, float* __restrict__ curve,
    const int step_k, const uint32_t nk0, const uint32_t nk1,
    const int has_noise) {
  if (flags->done) return;
  __shared__ __align__(16) float xs[NW][NDP];
  __shared__ __align__(16) float dr[NW][NDP];
  __shared__ __align__(16) float mh[NW][NDH];
  __shared__ float red[4 * NW];
  const int t = threadIdx.x;
  const int b = blockIdx.x;
  const int e0 = t << 2;

  float v[NW][4];
  #pragma unroll
  for (int w = 0; w < NW; ++w) {
    const float4 a = *reinterpret_cast<const float4*>(
        Sin + (size_t)(b * NW + w) * ND + e0);
    v[w][0]=a.x; v[w][1]=a.y; v[w][2]=a.z; v[w][3]=a.w;
  }
  if (has_noise && flags->apply_noise) {
    float p[NW];
    #pragma unroll
    for (int w = 0; w < NW; ++w) {
      const uint32_t rowbase = (uint32_t)(b * NW + w) * ND + (uint32_t)e0;
      #pragma unroll
      for (int j = 0; j < 4; ++j)
        v[w][j] = fmaf(0.01f, noise_z(nk0, nk1, rowbase + (uint32_t)j), v[w][j]);
      p[w] = v[w][0]*v[w][0] + v[w][1]*v[w][1] + v[w][2]*v[w][2] + v[w][3]*v[w][3];
    }
    block_sum6(p, red);
    #pragma unroll
    for (int w = 0; w < NW; ++w) {
      const float inv = 1.0f / (sqrtf(p[w]) + 1e-8f);
      #pragma unroll
      for (int j = 0; j < 4; ++j) v[w][j] *= inv;
    }
  }
  #pragma unroll
  for (int w = 0; w < NW; ++w) {
    float4 a; a.x=v[w][0]; a.y=v[w][1]; a.z=v[w][2]; a.w=v[w][3];
    *reinterpret_cast<float4*>(&xs[w][e0]) = a;
  }
  __syncthreads();

  for (int idx = t; idx < NW * NDH; idx += BT) {
    const int w = idx >> 7, el = idx & 127;
    float s = 0.0f;
    #pragma unroll
    for (int hh = 0; hh < NH; ++hh) s += xs[w][hh * NDH + el];
    mh[w][el] = s * 0.125f;
  }
  __syncthreads();

  {
    const int l = t & 63, wv = t >> 6;
    const int arow = l & 15, kg = l >> 4;
    #pragma unroll 1
    for (int h2 = 0; h2 < 2; ++h2) {
      const int hh = wv * 2 + h2;
      f32x4 acc0,acc1,acc2,acc3,acc4,acc5,acc6,acc7;
      acc0=acc1=acc2=acc3=acc4=acc5=acc6=acc7=(f32x4){0.f,0.f,0.f,0.f};
      f32x4* accp[8] = {&acc0,&acc1,&acc2,&acc3,&acc4,&acc5,&acc6,&acc7};
      #pragma unroll
      for (int ks = 0; ks < 4; ++ks) {
        short8v ahi = (short8v)0, alo = (short8v)0;
        if (arow < NW) {
          const float* xp = &xs[arow][hh * NDH + ks * 32 + kg * 8];
          const float4 xa = *reinterpret_cast<const float4*>(xp);
          const float4 xb = *reinterpret_cast<const float4*>(xp + 4);
          const float xf[8] = {xa.x,xa.y,xa.z,xa.w,xb.x,xb.y,xb.z,xb.w};
          #pragma unroll
          for (int j = 0; j < 8; ++j) {
            const unsigned short hi = f2bf(xf[j]);
            ahi[j] = (short)hi;
            alo[j] = (short)f2bf(xf[j] - bf2f(hi));
          }
        }
        #pragma unroll
        for (int nt = 0; nt < 8; ++nt) {
          const size_t fo = ((((size_t)(hh * 8 + nt)) * 4 + ks) * 64 + l) * 8;
          const short8v bhi = *reinterpret_cast<const short8v*>(Mhi + fo);
          const short8v blo = *reinterpret_cast<const short8v*>(Mlo + fo);
          f32x4 a = *accp[nt];
          a = __builtin_amdgcn_mfma_f32_16x16x32_bf16(alo, bhi, a, 0, 0, 0);
          a = __builtin_amdgcn_mfma_f32_16x16x32_bf16(ahi, blo, a, 0, 0, 0);
          a = __builtin_amdgcn_mfma_f32_16x16x32_bf16(ahi, bhi, a, 0, 0, 0);
          *accp[nt] = a;
        }
      }
      #pragma unroll
      for (int nt = 0; nt < 8; ++nt) {
        const f32x4 a = *accp[nt];
        #pragma unroll
        for (int r = 0; r < 4; ++r) {
          const int row = kg * 4 + r;
          if (row < NW) dr[row][hh * NDH + nt * 16 + arow] = a[r];
        }
      }
    }
  }
  __syncthreads();

  float acc[NW][4];
  #pragma unroll
  for (int w = 0; w < NW; ++w) {
    const float4 sg = *reinterpret_cast<const float4*>(
        signal + (size_t)(b * NW + w) * ND + e0);
    const float4 dv = *reinterpret_cast<const float4*>(&dr[w][e0]);
    const float4 xx = *reinterpret_cast<const float4*>(&xs[w][e0]);
    const float4 hh = *reinterpret_cast<const float4*>(&mh[w][e0 & 127]);
    const float sgf[4] = {sg.x, sg.y, sg.z, sg.w};
    const float dvf[4] = {dv.x, dv.y, dv.z, dv.w};
    const float xxf[4] = {xx.x, xx.y, xx.z, xx.w};
    const float mhf[4] = {hh.x, hh.y, hh.z, hh.w};
    #pragma unroll
    for (int j = 0; j < 4; ++j) {
      const float out = -dvf[j] + C_COUP * (mhf[j] - xxf[j]) + sgf[j];
      acc[w][j] = fmaf(C_DT, out, xxf[j]);
    }
  }

  float p[NW];
  #pragma unroll
  for (int w = 0; w < NW; ++w)
    p[w] = acc[w][0]*acc[w][0] + acc[w][1]*acc[w][1] +
           acc[w][2]*acc[w][2] + acc[w][3]*acc[w][3];
  block_sum6(p, red);
  float nn[NW][4];
  #pragma unroll
  for (int w = 0; w < NW; ++w) {
    const float n = sqrtf(p[w]);
    const float scale = fminf(fmaxf(n, 1e-3f), 12.0f) / fmaxf(n, 1e-8f);
    const float inv_norm = 1.0f / (n * scale + 1e-12f);
    float4 o;
    o.x = acc[w][0]*scale; o.y = acc[w][1]*scale;
    o.z = acc[w][2]*scale; o.w = acc[w][3]*scale;
    *reinterpret_cast<float4*>(Sout + (size_t)(b * NW + w) * ND + e0) = o;
    nn[w][0]=o.x*inv_norm; nn[w][1]=o.y*inv_norm;
    nn[w][2]=o.z*inv_norm; nn[w][3]=o.w*inv_norm;
  }

  float pc[NW];
  #pragma unroll
  for (int w = 0; w < NW; ++w) pc[w] = 0.0f;
  #pragma unroll
  for (int j = 0; j < 4; ++j) {
    float md = 0.0f;
    #pragma unroll
    for (int w = 0; w < NW; ++w) md += nn[w][j];
    md *= (1.0f / 6.0f);
    #pragma unroll
    for (int w = 0; w < NW; ++w) pc[w] = fmaf(nn[w][j], md, pc[w]);
  }
  block_sum6(pc, red);

  if (t == 0) {
    const float cos_sum = pc[0]+pc[1]+pc[2]+pc[3]+pc[4]+pc[5];
    const float T = 1.0f - cos_sum * (1.0f / 6.0f);
    atomicAdd(&flags->sum_T, T);
    if (T < C_TOL)   atomicAdd(&flags->cnt_low, 1);
    if (T > C_THIGH) atomicAdd(&flags->cnt_high, 1);
    __threadfence();
    const int ticket = atomicAdd(&flags->arrived, 1);
    if (ticket == NB - 1) {
      const float sT = atomicAdd(&flags->sum_T, 0.0f);
      const int cl = atomicAdd(&flags->cnt_low, 0);
      const int ch = atomicAdd(&flags->cnt_high, 0);
      curve[step_k] = sT * (1.0f / 2048.0f);
      const int nd = (cl == NB) ? 1 : 0;
      flags->apply_noise = (!nd && ch > 0) ? 1 : 0;
      flags->done = nd;
      flags->sum_T = 0.0f; flags->cnt_low = 0; flags->cnt_high = 0;
      flags->arrived = 0;
      __threadfence();
    }
  }
}

__global__ __launch_bounds__(256) void noise_kernel(float* __restrict__ S,
                                                    const Flags* __restrict__ flags,
                                                    const uint32_t k0, const uint32_t k1) {
  if (!flags->apply_noise) return;
  __shared__ float red[4];
  const int t = threadIdx.x;
  const uint32_t base = (uint32_t)blockIdx.x * ND + (t << 2);
  const float4 s = *reinterpret_cast<const float4*>(S + base);
  float v[4] = {s.x, s.y, s.z, s.w};
  #pragma unroll
  for (int j = 0; j < 4; ++j)
    v[j] = fmaf(0.01f, noise_z(k0, k1, base + (uint32_t)j), v[j]);
  const float p2 = v[0]*v[0] + v[1]*v[1] + v[2]*v[2] + v[3]*v[3];
  const float n2 = block_sum4(p2, red);
  const float inv = 1.0f / (sqrtf(n2) + 1e-8f);
  float4 o;
  o.x = v[0]*inv; o.y = v[1]*inv; o.z = v[2]*inv; o.w = v[3]*inv;
  *reinterpret_cast<float4*>(S + base) = o;
}

extern "C" void kernel_launch(void* const* d_in, const int* in_sizes, int n_in,
                              void* d_out, int out_size, void* d_ws, size_t ws_size,
                              hipStream_t stream) {
  const float* S0     = (const float*)d_in[0];
  const float* signal = (const float*)d_in[1];
  const float* U      = (const float*)d_in[2];
  const float* V      = (const float*)d_in[3];
  float* out   = (float*)d_out;
  float* curve = out + NTOT;
  Flags* flags = (Flags*)d_ws;
  Ctrl*  ctrl  = (Ctrl*)((char*)d_ws + 1024);
  unsigned short* Mhi = (unsigned short*)((char*)d_ws + 4096);             // 256 KB
  unsigned short* Mlo = (unsigned short*)((char*)d_ws + 4096 + 262144);    // 256 KB

  init_kernel<<<1, 64, 0, stream>>>(flags, ctrl, curve);
  precompute_M<<<NH * NDH, 128, 0, stream>>>(U, V, Mhi, Mlo);

  // fold_in(key(1), k) for k=0..15 on host: threefry((0,1), (0,k))
  uint32_t K0[NSTEPS], K1[NSTEPS];
  for (uint32_t k = 0; k < NSTEPS; ++k) tf2x32(0u, 1u, 0u, k, K0[k], K1[k]);

  // primary: persistent cooperative kernel (checked)
  const float* s0a = S0; float* outa = out; const float* siga = signal;
  const unsigned short* mha = Mhi; const unsigned short* mla = Mlo;
  Ctrl* ca = ctrl; float* cva = curve;
  void* args[] = {(void*)&s0a, (void*)&outa, (void*)&siga,
                  (void*)&mha, (void*)&mla, (void*)&ca, (void*)&cva};
  const hipError_t ce = hipLaunchCooperativeKernel(
      (const void*)dyn_kernel, dim3(NGRID), dim3(BT), args, 0, stream);
  if (ce != hipSuccess) {
    (void)hipGetLastError();   // clear sticky error
    // fallback: proven per-step path (round-5 semantics)
    for (int k = 0; k < NSTEPS; ++k) {
      step_kernel<<<NB, BT, 0, stream>>>(
          k == 0 ? S0 : out, out, signal, Mhi, Mlo, flags, curve, k,
          k > 0 ? K0[k - 1] : 0u, k > 0 ? K1[k - 1] : 0u, k > 0 ? 1 : 0);
    }
    noise_kernel<<<NB * NW, 256, 0, stream>>>(out, flags, K0[NSTEPS - 1], K1[NSTEPS - 1]);
  }
}

// Round 8
// 3302.730 us; speedup vs baseline: 1.1039x; 1.1039x over previous
//
#include <hip/hip_runtime.h>
#include <stdint.h>

#define NB 2048
#define NW 6
#define ND 1024
#define NH 8
#define NDH 128
#define NDP 1028          // padded LDS row stride (floats)
#define NTOT 12582912u
#define BT 256            // threads per block (4 waves)
#define NGRID 512         // 2 blocks/CU * 256 CU
#define BPB 4             // batch elements per block (coop path)
#define C_DT 0.09f
#define C_COUP 0.01f
#define C_TOL 0.05f
#define C_THIGH 0.22f
#define NSTEPS 16

typedef __attribute__((ext_vector_type(8))) short short8v;   // 8 bf16 (4 VGPR)
typedef __attribute__((ext_vector_type(4))) float f32x4;     // MFMA acc

struct Flags {           // fallback (per-step) control
  int done; int apply_noise; int cnt_low; int cnt_high; int arrived;
  float sum_T;
};
struct Ctrl {            // cooperative control (per-step slots, no resets)
  int arrived;           // monotonic across steps
  int release;           // last fully-published step count
  int done[NSTEPS];
  int apply[NSTEPS];
  int cnt_low[NSTEPS];
  int cnt_high[NSTEPS];
  float sum_T[NSTEPS];
};

__host__ __device__ __forceinline__ uint32_t rotl32(uint32_t x, uint32_t d) {
  return (x << d) | (x >> (32u - d));
}

// JAX threefry2x32 (20 rounds), matches jax/_src/prng.py
__host__ __device__ __forceinline__ void tf2x32(uint32_t k0, uint32_t k1,
                                                uint32_t x0, uint32_t x1,
                                                uint32_t& o0, uint32_t& o1) {
  const uint32_t k2 = k0 ^ k1 ^ 0x1BD11BDAu;
#define TF_R4(a,b,c,d) \
  x0 += x1; x1 = rotl32(x1,a); x1 ^= x0; \
  x0 += x1; x1 = rotl32(x1,b); x1 ^= x0; \
  x0 += x1; x1 = rotl32(x1,c); x1 ^= x0; \
  x0 += x1; x1 = rotl32(x1,d); x1 ^= x0;
  x0 += k0; x1 += k1;
  TF_R4(13u,15u,26u,6u)  x0 += k1; x1 += k2 + 1u;
  TF_R4(17u,29u,16u,24u) x0 += k2; x1 += k0 + 2u;
  TF_R4(13u,15u,26u,6u)  x0 += k0; x1 += k1 + 3u;
  TF_R4(17u,29u,16u,24u) x0 += k1; x1 += k2 + 4u;
  TF_R4(13u,15u,26u,6u)  x0 += k2; x1 += k0 + 5u;
#undef TF_R4
  o0 = x0; o1 = x1;
}

// XLA ErfInv32 (Giles) polynomial — matches xla/client/lib/math.cc
__device__ __forceinline__ float erfinv_xla(float x) {
  const float w = -log1pf(-x * x);
  float ps, pb;
  const float ws = w - 2.5f;
  ps = 2.81022636e-08f;
  ps = fmaf(ps, ws, 3.43273939e-07f);
  ps = fmaf(ps, ws, -3.5233877e-06f);
  ps = fmaf(ps, ws, -4.39150654e-06f);
  ps = fmaf(ps, ws, 0.00021858087f);
  ps = fmaf(ps, ws, -0.00125372503f);
  ps = fmaf(ps, ws, -0.00417768164f);
  ps = fmaf(ps, ws, 0.246640727f);
  ps = fmaf(ps, ws, 1.50140941f);
  const float wb = sqrtf(w) - 3.0f;
  pb = -0.000200214257f;
  pb = fmaf(pb, wb, 0.000100950558f);
  pb = fmaf(pb, wb, 0.00134934322f);
  pb = fmaf(pb, wb, -0.00367342844f);
  pb = fmaf(pb, wb, 0.00573950773f);
  pb = fmaf(pb, wb, -0.0076224613f);
  pb = fmaf(pb, wb, 0.00943887047f);
  pb = fmaf(pb, wb, 1.00167406f);
  pb = fmaf(pb, wb, 2.83297682f);
  const float p = (w < 5.0f) ? ps : pb;
  return p * x;
}

__device__ __forceinline__ float noise_z(uint32_t k0, uint32_t k1, uint32_t p) {
  // JAX threefry_partitionable: counter (hi=0, lo=p), bits = o0 ^ o1
  uint32_t o0, o1;
  tf2x32(k0, k1, 0u, p, o0, o1);
  const uint32_t bits = o0 ^ o1;
  const float f = __uint_as_float((bits >> 9) | 0x3F800000u) - 1.0f;
  const float lo = -0.99999994f;                 // nextafter(-1,0) in f32
  const float u = fmaxf(lo, fmaf(f, 2.0f, lo));
  return 1.41421356237f * erfinv_xla(u);
}

// f32 -> bf16 round-to-nearest-even
__device__ __forceinline__ unsigned short f2bf(float f) {
  const uint32_t u = __float_as_uint(f);
  return (unsigned short)((u + 0x7FFFu + ((u >> 16) & 1u)) >> 16);
}
__device__ __forceinline__ float bf2f(unsigned short h) {
  return __uint_as_float(((uint32_t)h) << 16);
}

// Batched 6-value block reduction for BT=256 (4 waves): 36 shuffles, 2 syncs.
__device__ __forceinline__ void block_sum6(float p[NW], float* red /*[4*NW]*/) {
  #pragma unroll
  for (int w = 0; w < NW; ++w)
    #pragma unroll
    for (int off = 32; off > 0; off >>= 1) p[w] += __shfl_down(p[w], off, 64);
  const int t = threadIdx.x;
  __syncthreads();                       // protect red from previous use
  if ((t & 63) == 0) {
    #pragma unroll
    for (int w = 0; w < NW; ++w) red[(t >> 6) * NW + w] = p[w];
  }
  __syncthreads();
  #pragma unroll
  for (int w = 0; w < NW; ++w)
    p[w] = red[w] + red[NW + w] + red[2 * NW + w] + red[3 * NW + w];
}

// single-value block reduce for 256-thread trailing noise kernel
__device__ __forceinline__ float block_sum4(float v, float* red) {
  #pragma unroll
  for (int off = 32; off > 0; off >>= 1) v += __shfl_down(v, off, 64);
  const int t = threadIdx.x;
  __syncthreads();
  if ((t & 63) == 0) red[t >> 6] = v;
  __syncthreads();
  return red[0] + red[1] + red[2] + red[3];
}

__global__ void init_kernel(Flags* f, Ctrl* c, float* curve) {
  const int t = threadIdx.x;
  if (t == 0) {
    f->done = 0; f->apply_noise = 0;
    f->cnt_low = 0; f->cnt_high = 0; f->arrived = 0; f->sum_T = 0.0f;
    c->arrived = 0; c->release = 0;
  }
  if (t < NSTEPS) {
    c->done[t] = 0; c->apply[t] = 0;
    c->cnt_low[t] = 0; c->cnt_high[t] = 0; c->sum_T[t] = 0.0f;
    curve[t] = __int_as_float(0x7FC00000);   // NaN
  }
}

// M[h][d][e] = sum_r U[h][d][r] * V[h][r][e], bf16 hi/lo in B-fragment order:
// frag = ((h*8 + nt)*4 + ks)*64 + lane, 8 bf16 each;
// lane = (e&15) | ((d>>3)&3)<<4, j = d&7, nt = e>>4, ks = d>>5.
__global__ __launch_bounds__(128) void precompute_M(const float* __restrict__ U,
                                                    const float* __restrict__ V,
                                                    unsigned short* __restrict__ Mhi,
                                                    unsigned short* __restrict__ Mlo) {
  const int hd = blockIdx.x;          // h*128 + d
  const int h = hd >> 7;
  const int d = hd & 127;
  const int e = threadIdx.x;
  __shared__ float u[64];
  if (e < 64) u[e] = U[hd * 64 + e];
  __syncthreads();
  float acc = 0.0f;
  #pragma unroll
  for (int r = 0; r < 64; ++r)
    acc = fmaf(u[r], V[(h * 64 + r) * 128 + e], acc);
  const unsigned short hi = f2bf(acc);
  const unsigned short lo = f2bf(acc - bf2f(hi));
  const int nt = e >> 4, ks = d >> 5;
  const int lane = (e & 15) | (((d >> 3) & 3) << 4);
  const int j = d & 7;
  const size_t idx = ((((size_t)(h * 8 + nt)) * 4 + ks) * 64 + lane) * 8 + j;
  Mhi[idx] = hi; Mlo[idx] = lo;
}

// ===================== cooperative (persistent) path =====================
// Hand-rolled grid barrier (NO cg::grid_group::sync — that is an opaque call
// that forces caller-saved spills of the register-resident S state).
__global__ __launch_bounds__(BT, 2) void dyn_kernel(
    const float* __restrict__ S0, float* __restrict__ outS,
    const float* __restrict__ signal,
    const unsigned short* __restrict__ Mhi, const unsigned short* __restrict__ Mlo,
    Ctrl* __restrict__ ctrl, float* __restrict__ curve) {
  __shared__ __align__(16) float xs2[2][NW][NDP];   // 48.2 KB: x, then drift (in-place)
  __shared__ __align__(16) float mh2[2][NW][NDH];   // 6 KB
  __shared__ float red[4 * NW];
  __shared__ int bc[2];
  const int t = threadIdx.x;
  const int g = blockIdx.x;
  const int e0 = t << 2;              // 4 cols per thread (elementwise phases)

  // persistent state: 4 batch elements, 24 f32 each per thread (96 VGPR)
  float S[BPB][NW][4];
  #pragma unroll
  for (int i = 0; i < BPB; ++i) {
    const int b = g * BPB + i;
    #pragma unroll
    for (int w = 0; w < NW; ++w) {
      const float4 a = *reinterpret_cast<const float4*>(
          S0 + (size_t)(b * NW + w) * ND + e0);
      S[i][w][0]=a.x; S[i][w][1]=a.y; S[i][w][2]=a.z; S[i][w][3]=a.w;
    }
  }
  float Tb[BPB];                      // only thread 0's copy is meaningful

  int broke = 0;
  for (int k = 0; k < NSTEPS; ++k) {
    if (k > 0) {
      if (t == 0) {
        bc[0] = atomicAdd(&ctrl->done[k - 1], 0);
        bc[1] = atomicAdd(&ctrl->apply[k - 1], 0);
      }
      __syncthreads();
      const int done_prev = bc[0];
      const int appl = bc[1];
      if (done_prev) { broke = 1; break; }
      if (appl) {   // pending noise of step k-1, in registers
        uint32_t nk0, nk1; tf2x32(0u, 1u, 0u, (uint32_t)(k - 1), nk0, nk1);
        #pragma unroll
        for (int i = 0; i < BPB; ++i) {
          const uint32_t bb = (uint32_t)(g * BPB + i);
          float p[NW];
          #pragma unroll
          for (int w = 0; w < NW; ++w) {
            const uint32_t rowbase = (bb * NW + (uint32_t)w) * ND + (uint32_t)e0;
            #pragma unroll
            for (int j = 0; j < 4; ++j)
              S[i][w][j] = fmaf(0.01f, noise_z(nk0, nk1, rowbase + (uint32_t)j),
                                S[i][w][j]);
            p[w] = S[i][w][0]*S[i][w][0] + S[i][w][1]*S[i][w][1] +
                   S[i][w][2]*S[i][w][2] + S[i][w][3]*S[i][w][3];
          }
          block_sum6(p, red);
          #pragma unroll
          for (int w = 0; w < NW; ++w) {
            const float inv = 1.0f / (sqrtf(p[w]) + 1e-8f);
            #pragma unroll
            for (int j = 0; j < 4; ++j) S[i][w][j] *= inv;
          }
        }
      }
    }

    // ---- two MFMA passes, 2 batch elements each (rows 0-5 / 8-13) ----
    #pragma unroll
    for (int ps = 0; ps < 2; ++ps) {
      #pragma unroll
      for (int i = 0; i < 2; ++i) {
        #pragma unroll
        for (int w = 0; w < NW; ++w) {
          float4 a;
          a.x = S[ps*2+i][w][0]; a.y = S[ps*2+i][w][1];
          a.z = S[ps*2+i][w][2]; a.w = S[ps*2+i][w][3];
          *reinterpret_cast<float4*>(&xs2[i][w][e0]) = a;
        }
      }
      __syncthreads();
      for (int idx = t; idx < 2 * NW * NDH; idx += BT) {   // 6 iters
        const int i = idx / (NW * NDH);
        const int r = idx - i * (NW * NDH);
        const int w = r >> 7, el = r & 127;
        float s = 0.0f;
        #pragma unroll
        for (int hh = 0; hh < NH; ++hh) s += xs2[i][w][hh * NDH + el];
        mh2[i][w][el] = s * 0.125f;
      }
      __syncthreads();
      {
        const int l = t & 63, wv = t >> 6;
        const int arow = l & 15, kg = l >> 4;
        const int ai = arow >> 3, ar = arow & 7;
        #pragma unroll 1
        for (int h2 = 0; h2 < 2; ++h2) {
          const int hh = wv * 2 + h2;
          f32x4 acc0,acc1,acc2,acc3,acc4,acc5,acc6,acc7;
          acc0=acc1=acc2=acc3=acc4=acc5=acc6=acc7=(f32x4){0.f,0.f,0.f,0.f};
          f32x4* accp[8] = {&acc0,&acc1,&acc2,&acc3,&acc4,&acc5,&acc6,&acc7};
          #pragma unroll
          for (int ks = 0; ks < 4; ++ks) {
            short8v ahi = (short8v)0, alo = (short8v)0;
            if (ar < NW) {
              const float* xp = &xs2[ai][ar][hh * NDH + ks * 32 + kg * 8];
              const float4 xa = *reinterpret_cast<const float4*>(xp);
              const float4 xb = *reinterpret_cast<const float4*>(xp + 4);
              const float xf[8] = {xa.x,xa.y,xa.z,xa.w,xb.x,xb.y,xb.z,xb.w};
              #pragma unroll
              for (int j = 0; j < 8; ++j) {
                const unsigned short hi = f2bf(xf[j]);
                ahi[j] = (short)hi;
                alo[j] = (short)f2bf(xf[j] - bf2f(hi));
              }
            }
            #pragma unroll
            for (int nt = 0; nt < 8; ++nt) {
              const size_t fo = ((((size_t)(hh * 8 + nt)) * 4 + ks) * 64 + l) * 8;
              const short8v bhi = *reinterpret_cast<const short8v*>(Mhi + fo);
              const short8v blo = *reinterpret_cast<const short8v*>(Mlo + fo);
              f32x4 a = *accp[nt];
              a = __builtin_amdgcn_mfma_f32_16x16x32_bf16(alo, bhi, a, 0, 0, 0);
              a = __builtin_amdgcn_mfma_f32_16x16x32_bf16(ahi, blo, a, 0, 0, 0);
              a = __builtin_amdgcn_mfma_f32_16x16x32_bf16(ahi, bhi, a, 0, 0, 0);
              *accp[nt] = a;
            }
          }
          #pragma unroll
          for (int nt = 0; nt < 8; ++nt) {
            const f32x4 a = *accp[nt];
            #pragma unroll
            for (int r = 0; r < 4; ++r) {
              const int row = kg * 4 + r;
              const int ci = row >> 3, cr = row & 7;
              if (cr < NW) xs2[ci][cr][hh * NDH + nt * 16 + arow] = a[r];
            }
          }
        }
      }
      __syncthreads();
      #pragma unroll
      for (int i = 0; i < 2; ++i) {
        const int ib = ps * 2 + i;
        const int b = g * BPB + ib;
        float acc[NW][4];
        float p[NW];
        #pragma unroll
        for (int w = 0; w < NW; ++w) {
          const float4 sg = *reinterpret_cast<const float4*>(
              signal + (size_t)(b * NW + w) * ND + e0);
          const float4 dv = *reinterpret_cast<const float4*>(&xs2[i][w][e0]);
          const float4 hh = *reinterpret_cast<const float4*>(&mh2[i][w][e0 & 127]);
          const float sgf[4] = {sg.x, sg.y, sg.z, sg.w};
          const float dvf[4] = {dv.x, dv.y, dv.z, dv.w};
          const float mhf[4] = {hh.x, hh.y, hh.z, hh.w};
          float s2 = 0.0f;
          #pragma unroll
          for (int j = 0; j < 4; ++j) {
            const float out = -dvf[j] + C_COUP * (mhf[j] - S[ib][w][j]) + sgf[j];
            acc[w][j] = fmaf(C_DT, out, S[ib][w][j]);
            s2 = fmaf(acc[w][j], acc[w][j], s2);
          }
          p[w] = s2;
        }
        block_sum6(p, red);
        #pragma unroll
        for (int w = 0; w < NW; ++w) {
          const float n = sqrtf(p[w]);
          const float scale = fminf(fmaxf(n, 1e-3f), 12.0f) / fmaxf(n, 1e-8f);
          const float inv_norm = 1.0f / (n * scale + 1e-12f);
          #pragma unroll
          for (int j = 0; j < 4; ++j) {
            const float o = acc[w][j] * scale;
            S[ib][w][j] = o;                 // new state
            acc[w][j] = o * inv_norm;        // normed, for tension
          }
        }
        float pc[NW];
        #pragma unroll
        for (int w = 0; w < NW; ++w) pc[w] = 0.0f;
        #pragma unroll
        for (int j = 0; j < 4; ++j) {
          float md = 0.0f;
          #pragma unroll
          for (int w = 0; w < NW; ++w) md += acc[w][j];
          md *= (1.0f / 6.0f);
          #pragma unroll
          for (int w = 0; w < NW; ++w) pc[w] = fmaf(acc[w][j], md, pc[w]);
        }
        block_sum6(pc, red);
        if (t == 0)
          Tb[ib] = 1.0f - (pc[0]+pc[1]+pc[2]+pc[3]+pc[4]+pc[5]) * (1.0f / 6.0f);
      }
    }  // passes

    // ---- hand-rolled grid barrier + flags publish (no opaque calls) ----
    if (t == 0) {
      float st = 0.0f; int cl = 0, ch = 0;
      #pragma unroll
      for (int i = 0; i < BPB; ++i) {
        st += Tb[i];
        cl += (Tb[i] < C_TOL) ? 1 : 0;
        ch += (Tb[i] > C_THIGH) ? 1 : 0;
      }
      atomicAdd(&ctrl->sum_T[k], st);
      if (cl) atomicAdd(&ctrl->cnt_low[k], cl);
      if (ch) atomicAdd(&ctrl->cnt_high[k], ch);
      __threadfence();
      const int ticket = atomicAdd(&ctrl->arrived, 1);
      if (ticket == (k + 1) * NGRID - 1) {
        const float sT = atomicAdd(&ctrl->sum_T[k], 0.0f);
        const int cln = atomicAdd(&ctrl->cnt_low[k], 0);
        const int chn = atomicAdd(&ctrl->cnt_high[k], 0);
        curve[k] = sT * (1.0f / 2048.0f);
        const int nd = (cln == NB) ? 1 : 0;
        atomicExch(&ctrl->done[k], nd);
        atomicExch(&ctrl->apply[k], (!nd && chn > 0) ? 1 : 0);
        __threadfence();
        atomicExch(&ctrl->release, k + 1);   // release the grid
      } else {
        while (atomicAdd(&ctrl->release, 0) < k + 1)
          __builtin_amdgcn_s_sleep(8);
      }
      __threadfence();
    }
    __syncthreads();
  }  // steps

  if (!broke) {   // trailing pending noise of the final executed step
    if (t == 0) bc[0] = atomicAdd(&ctrl->apply[NSTEPS - 1], 0);
    __syncthreads();
    if (bc[0]) {
      uint32_t nk0, nk1; tf2x32(0u, 1u, 0u, (uint32_t)(NSTEPS - 1), nk0, nk1);
      #pragma unroll
      for (int i = 0; i < BPB; ++i) {
        const uint32_t bb = (uint32_t)(g * BPB + i);
        float p[NW];
        #pragma unroll
        for (int w = 0; w < NW; ++w) {
          const uint32_t rowbase = (bb * NW + (uint32_t)w) * ND + (uint32_t)e0;
          #pragma unroll
          for (int j = 0; j < 4; ++j)
            S[i][w][j] = fmaf(0.01f, noise_z(nk0, nk1, rowbase + (uint32_t)j),
                              S[i][w][j]);
          p[w] = S[i][w][0]*S[i][w][0] + S[i][w][1]*S[i][w][1] +
                 S[i][w][2]*S[i][w][2] + S[i][w][3]*S[i][w][3];
        }
        block_sum6(p, red);
        #pragma unroll
        for (int w = 0; w < NW; ++w) {
          const float inv = 1.0f / (sqrtf(p[w]) + 1e-8f);
          #pragma unroll
          for (int j = 0; j < 4; ++j) S[i][w][j] *= inv;
        }
      }
    }
  }

  #pragma unroll
  for (int i = 0; i < BPB; ++i) {
    const int b = g * BPB + i;
    #pragma unroll
    for (int w = 0; w < NW; ++w) {
      float4 a;
      a.x = S[i][w][0]; a.y = S[i][w][1]; a.z = S[i][w][2]; a.w = S[i][w][3];
      *reinterpret_cast<float4*>(outS + (size_t)(b * NW + w) * ND + e0) = a;
    }
  }
}

// ===================== fallback (per-step) path — round-5, proven ==========
__global__ __launch_bounds__(BT, 3) void step_kernel(
    const float* __restrict__ Sin, float* __restrict__ Sout,
    const float* __restrict__ signal,
    const unsigned short* __restrict__ Mhi, const unsigned short* __restrict__ Mlo,
    Flags* __restrict__ flags, float* __restrict__ curve,
    const int step_k, const uint32_t nk0, const uint32_t nk1,
    const int has_noise) {
  if (flags->done) return;
  __shared__ __align__(16) float xs[NW][NDP];
  __shared__ __align__(16) float dr[NW][NDP];
  __shared__ __align__(16) float mh[NW][NDH];
  __shared__ float red[4 * NW];
  const int t = threadIdx.x;
  const int b = blockIdx.x;
  const int e0 = t << 2;

  float v[NW][4];
  #pragma unroll
  for (int w = 0; w < NW; ++w) {
    const float4 a = *reinterpret_cast<const float4*>(
        Sin + (size_t)(b * NW + w) * ND + e0);
    v[w][0]=a.x; v[w][1]=a.y; v[w][2]=a.z; v[w][3]=a.w;
  }
  if (has_noise && flags->apply_noise) {
    float p[NW];
    #pragma unroll
    for (int w = 0; w < NW; ++w) {
      const uint32_t rowbase = (uint32_t)(b * NW + w) * ND + (uint32_t)e0;
      #pragma unroll
      for (int j = 0; j < 4; ++j)
        v[w][j] = fmaf(0.01f, noise_z(nk0, nk1, rowbase + (uint32_t)j), v[w][j]);
      p[w] = v[w][0]*v[w][0] + v[w][1]*v[w][1] + v[w][2]*v[w][2] + v[w][3]*v[w][3];
    }
    block_sum6(p, red);
    #pragma unroll
    for (int w = 0; w < NW; ++w) {
      const float inv = 1.0f / (sqrtf(p[w]) + 1e-8f);
      #pragma unroll
      for (int j = 0; j < 4; ++j) v[w][j] *= inv;
    }
  }
  #pragma unroll
  for (int w = 0; w < NW; ++w) {
    float4 a; a.x=v[w][0]; a.y=v[w][1]; a.z=v[w][2]; a.w=v[w][3];
    *reinterpret_cast<float4*>(&xs[w][e0]) = a;
  }
  __syncthreads();

  for (int idx = t; idx < NW * NDH; idx += BT) {
    const int w = idx >> 7, el = idx & 127;
    float s = 0.0f;
    #pragma unroll
    for (int hh = 0; hh < NH; ++hh) s += xs[w][hh * NDH + el];
    mh[w][el] = s * 0.125f;
  }
  __syncthreads();

  {
    const int l = t & 63, wv = t >> 6;
    const int arow = l & 15, kg = l >> 4;
    #pragma unroll 1
    for (int h2 = 0; h2 < 2; ++h2) {
      const int hh = wv * 2 + h2;
      f32x4 acc0,acc1,acc2,acc3,acc4,acc5,acc6,acc7;
      acc0=acc1=acc2=acc3=acc4=acc5=acc6=acc7=(f32x4){0.f,0.f,0.f,0.f};
      f32x4* accp[8] = {&acc0,&acc1,&acc2,&acc3,&acc4,&acc5,&acc6,&acc7};
      #pragma unroll
      for (int ks = 0; ks < 4; ++ks) {
        short8v ahi = (short8v)0, alo = (short8v)0;
        if (arow < NW) {
          const float* xp = &xs[arow][hh * NDH + ks * 32 + kg * 8];
          const float4 xa = *reinterpret_cast<const float4*>(xp);
          const float4 xb = *reinterpret_cast<const float4*>(xp + 4);
          const float xf[8] = {xa.x,xa.y,xa.z,xa.w,xb.x,xb.y,xb.z,xb.w};
          #pragma unroll
          for (int j = 0; j < 8; ++j) {
            const unsigned short hi = f2bf(xf[j]);
            ahi[j] = (short)hi;
            alo[j] = (short)f2bf(xf[j] - bf2f(hi));
          }
        }
        #pragma unroll
        for (int nt = 0; nt < 8; ++nt) {
          const size_t fo = ((((size_t)(hh * 8 + nt)) * 4 + ks) * 64 + l) * 8;
          const short8v bhi = *reinterpret_cast<const short8v*>(Mhi + fo);
          const short8v blo = *reinterpret_cast<const short8v*>(Mlo + fo);
          f32x4 a = *accp[nt];
          a = __builtin_amdgcn_mfma_f32_16x16x32_bf16(alo, bhi, a, 0, 0, 0);
          a = __builtin_amdgcn_mfma_f32_16x16x32_bf16(ahi, blo, a, 0, 0, 0);
          a = __builtin_amdgcn_mfma_f32_16x16x32_bf16(ahi, bhi, a, 0, 0, 0);
          *accp[nt] = a;
        }
      }
      #pragma unroll
      for (int nt = 0; nt < 8; ++nt) {
        const f32x4 a = *accp[nt];
        #pragma unroll
        for (int r = 0; r < 4; ++r) {
          const int row = kg * 4 + r;
          if (row < NW) dr[row][hh * NDH + nt * 16 + arow] = a[r];
        }
      }
    }
  }
  __syncthreads();

  float acc[NW][4];
  #pragma unroll
  for (int w = 0; w < NW; ++w) {
    const float4 sg = *reinterpret_cast<const float4*>(
        signal + (size_t)(b * NW + w) * ND + e0);
    const float4 dv = *reinterpret_cast<const float4*>(&dr[w][e0]);
    const float4 xx = *reinterpret_cast<const float4*>(&xs[w][e0]);
    const float4 hh = *reinterpret_cast<const float4*>(&mh[w][e0 & 127]);
    const float sgf[4] = {sg.x, sg.y, sg.z, sg.w};
    const float dvf[4] = {dv.x, dv.y, dv.z, dv.w};
    const float xxf[4] = {xx.x, xx.y, xx.z, xx.w};
    const float mhf[4] = {hh.x, hh.y, hh.z, hh.w};
    #pragma unroll
    for (int j = 0; j < 4; ++j) {
      const float out = -dvf[j] + C_COUP * (mhf[j] - xxf[j]) + sgf[j];
      acc[w][j] = fmaf(C_DT, out, xxf[j]);
    }
  }

  float p[NW];
  #pragma unroll
  for (int w = 0; w < NW; ++w)
    p[w] = acc[w][0]*acc[w][0] + acc[w][1]*acc[w][1] +
           acc[w][2]*acc[w][2] + acc[w][3]*acc[w][3];
  block_sum6(p, red);
  float nn[NW][4];
  #pragma unroll
  for (int w = 0; w < NW; ++w) {
    const float n = sqrtf(p[w]);
    const float scale = fminf(fmaxf(n, 1e-3f), 12.0f) / fmaxf(n, 1e-8f);
    const float inv_norm = 1.0f / (n * scale + 1e-12f);
    float4 o;
    o.x = acc[w][0]*scale; o.y = acc[w][1]*scale;
    o.z = acc[w][2]*scale; o.w = acc[w][3]*scale;
    *reinterpret_cast<float4*>(Sout + (size_t)(b * NW + w) * ND + e0) = o;
    nn[w][0]=o.x*inv_norm; nn[w][1]=o.y*inv_norm;
    nn[w][2]=o.z*inv_norm; nn[w][3]=o.w*inv_norm;
  }

  float pc[NW];
  #pragma unroll
  for (int w = 0; w < NW; ++w) pc[w] = 0.0f;
  #pragma unroll
  for (int j = 0; j < 4; ++j) {
    float md = 0.0f;
    #pragma unroll
    for (int w = 0; w < NW; ++w) md += nn[w][j];
    md *= (1.0f / 6.0f);
    #pragma unroll
    for (int w = 0; w < NW; ++w) pc[w] = fmaf(nn[w][j], md, pc[w]);
  }
  block_sum6(pc, red);

  if (t == 0) {
    const float cos_sum = pc[0]+pc[1]+pc[2]+pc[3]+pc[4]+pc[5];
    const float T = 1.0f - cos_sum * (1.0f / 6.0f);
    atomicAdd(&flags->sum_T, T);
    if (T < C_TOL)   atomicAdd(&flags->cnt_low, 1);
    if (T > C_THIGH) atomicAdd(&flags->cnt_high, 1);
    __threadfence();
    const int ticket = atomicAdd(&flags->arrived, 1);
    if (ticket == NB - 1) {
      const float sT = atomicAdd(&flags->sum_T, 0.0f);
      const int cl = atomicAdd(&flags->cnt_low, 0);
      const int ch = atomicAdd(&flags->cnt_high, 0);
      curve[step_k] = sT * (1.0f / 2048.0f);
      const int nd = (cl == NB) ? 1 : 0;
      flags->apply_noise = (!nd && ch > 0) ? 1 : 0;
      flags->done = nd;
      flags->sum_T = 0.0f; flags->cnt_low = 0; flags->cnt_high = 0;
      flags->arrived = 0;
      __threadfence();
    }
  }
}

__global__ __launch_bounds__(256) void noise_kernel(float* __restrict__ S,
                                                    const Flags* __restrict__ flags,
                                                    const uint32_t k0, const uint32_t k1) {
  if (!flags->apply_noise) return;
  __shared__ float red[4];
  const int t = threadIdx.x;
  const uint32_t base = (uint32_t)blockIdx.x * ND + (t << 2);
  const float4 s = *reinterpret_cast<const float4*>(S + base);
  float v[4] = {s.x, s.y, s.z, s.w};
  #pragma unroll
  for (int j = 0; j < 4; ++j)
    v[j] = fmaf(0.01f, noise_z(k0, k1, base + (uint32_t)j), v[j]);
  const float p2 = v[0]*v[0] + v[1]*v[1] + v[2]*v[2] + v[3]*v[3];
  const float n2 = block_sum4(p2, red);
  const float inv = 1.0f / (sqrtf(n2) + 1e-8f);
  float4 o;
  o.x = v[0]*inv; o.y = v[1]*inv; o.z = v[2]*inv; o.w = v[3]*inv;
  *reinterpret_cast<float4*>(S + base) = o;
}

extern "C" void kernel_launch(void* const* d_in, const int* in_sizes, int n_in,
                              void* d_out, int out_size, void* d_ws, size_t ws_size,
                              hipStream_t stream) {
  const float* S0     = (const float*)d_in[0];
  const float* signal = (const float*)d_in[1];
  const float* U      = (const float*)d_in[2];
  const float* V      = (const float*)d_in[3];
  float* out   = (float*)d_out;
  float* curve = out + NTOT;
  Flags* flags = (Flags*)d_ws;
  Ctrl*  ctrl  = (Ctrl*)((char*)d_ws + 1024);
  unsigned short* Mhi = (unsigned short*)((char*)d_ws + 4096);             // 256 KB
  unsigned short* Mlo = (unsigned short*)((char*)d_ws + 4096 + 262144);    // 256 KB

  init_kernel<<<1, 64, 0, stream>>>(flags, ctrl, curve);
  precompute_M<<<NH * NDH, 128, 0, stream>>>(U, V, Mhi, Mlo);

  // fold_in(key(1), k) for k=0..15 on host: threefry((0,1), (0,k))
  uint32_t K0[NSTEPS], K1[NSTEPS];
  for (uint32_t k = 0; k < NSTEPS; ++k) tf2x32(0u, 1u, 0u, k, K0[k], K1[k]);

  // primary: persistent cooperative kernel (checked)
  const float* s0a = S0; float* outa = out; const float* siga = signal;
  const unsigned short* mha = Mhi; const unsigned short* mla = Mlo;
  Ctrl* ca = ctrl; float* cva = curve;
  void* args[] = {(void*)&s0a, (void*)&outa, (void*)&siga,
                  (void*)&mha, (void*)&mla, (void*)&ca, (void*)&cva};
  const hipError_t ce = hipLaunchCooperativeKernel(
      (const void*)dyn_kernel, dim3(NGRID), dim3(BT), args, 0, stream);
  if (ce != hipSuccess) {
    (void)hipGetLastError();   // clear sticky error
    // fallback: proven per-step path (round-5 semantics)
    for (int k = 0; k < NSTEPS; ++k) {
      step_kernel<<<NB, BT, 0, stream>>>(
          k == 0 ? S0 : out, out, signal, Mhi, Mlo, flags, curve, k,
          k > 0 ? K0[k - 1] : 0u, k > 0 ? K1[k - 1] : 0u, k > 0 ? 1 : 0);
    }
    noise_kernel<<<NB * NW, 256, 0, stream>>>(out, flags, K0[NSTEPS - 1], K1[NSTEPS - 1]);
  }
}

// Round 9
// 2200.319 us; speedup vs baseline: 1.6570x; 1.5010x over previous
//
#include <hip/hip_runtime.h>
#include <stdint.h>

#define NB 2048
#define NW 6
#define ND 1024
#define NH 8
#define NDH 128
#define NDP 1028          // padded LDS row stride (floats)
#define NTOT 12582912u
#define BT 256            // threads per step-kernel block (4 waves)
#define C_DT 0.09f
#define C_COUP 0.01f
#define C_TOL 0.05f
#define C_THIGH 0.22f
#define NSTEPS 16

typedef __attribute__((ext_vector_type(8))) short short8v;   // 8 bf16 (4 VGPR)
typedef __attribute__((ext_vector_type(4))) float f32x4;     // MFMA acc

struct Flags {
  int done; int apply_noise; int cnt_low; int cnt_high; int arrived;
  float sum_T;
};

__host__ __device__ __forceinline__ uint32_t rotl32(uint32_t x, uint32_t d) {
  return (x << d) | (x >> (32u - d));
}

// JAX threefry2x32 (20 rounds), matches jax/_src/prng.py
__host__ __device__ __forceinline__ void tf2x32(uint32_t k0, uint32_t k1,
                                                uint32_t x0, uint32_t x1,
                                                uint32_t& o0, uint32_t& o1) {
  const uint32_t k2 = k0 ^ k1 ^ 0x1BD11BDAu;
#define TF_R4(a,b,c,d) \
  x0 += x1; x1 = rotl32(x1,a); x1 ^= x0; \
  x0 += x1; x1 = rotl32(x1,b); x1 ^= x0; \
  x0 += x1; x1 = rotl32(x1,c); x1 ^= x0; \
  x0 += x1; x1 = rotl32(x1,d); x1 ^= x0;
  x0 += k0; x1 += k1;
  TF_R4(13u,15u,26u,6u)  x0 += k1; x1 += k2 + 1u;
  TF_R4(17u,29u,16u,24u) x0 += k2; x1 += k0 + 2u;
  TF_R4(13u,15u,26u,6u)  x0 += k0; x1 += k1 + 3u;
  TF_R4(17u,29u,16u,24u) x0 += k1; x1 += k2 + 4u;
  TF_R4(13u,15u,26u,6u)  x0 += k2; x1 += k0 + 5u;
#undef TF_R4
  o0 = x0; o1 = x1;
}

// XLA ErfInv32 (Giles) polynomial — matches xla/client/lib/math.cc
__device__ __forceinline__ float erfinv_xla(float x) {
  const float w = -log1pf(-x * x);
  float ps, pb;
  const float ws = w - 2.5f;
  ps = 2.81022636e-08f;
  ps = fmaf(ps, ws, 3.43273939e-07f);
  ps = fmaf(ps, ws, -3.5233877e-06f);
  ps = fmaf(ps, ws, -4.39150654e-06f);
  ps = fmaf(ps, ws, 0.00021858087f);
  ps = fmaf(ps, ws, -0.00125372503f);
  ps = fmaf(ps, ws, -0.00417768164f);
  ps = fmaf(ps, ws, 0.246640727f);
  ps = fmaf(ps, ws, 1.50140941f);
  const float wb = sqrtf(w) - 3.0f;
  pb = -0.000200214257f;
  pb = fmaf(pb, wb, 0.000100950558f);
  pb = fmaf(pb, wb, 0.00134934322f);
  pb = fmaf(pb, wb, -0.00367342844f);
  pb = fmaf(pb, wb, 0.00573950773f);
  pb = fmaf(pb, wb, -0.0076224613f);
  pb = fmaf(pb, wb, 0.00943887047f);
  pb = fmaf(pb, wb, 1.00167406f);
  pb = fmaf(pb, wb, 2.83297682f);
  const float p = (w < 5.0f) ? ps : pb;
  return p * x;
}

__device__ __forceinline__ float noise_z(uint32_t k0, uint32_t k1, uint32_t p) {
  // JAX threefry_partitionable: counter (hi=0, lo=p), bits = o0 ^ o1
  uint32_t o0, o1;
  tf2x32(k0, k1, 0u, p, o0, o1);
  const uint32_t bits = o0 ^ o1;
  const float f = __uint_as_float((bits >> 9) | 0x3F800000u) - 1.0f;
  const float lo = -0.99999994f;                 // nextafter(-1,0) in f32
  const float u = fmaxf(lo, fmaf(f, 2.0f, lo));
  return 1.41421356237f * erfinv_xla(u);
}

// f32 -> bf16 round-to-nearest-even
__device__ __forceinline__ unsigned short f2bf(float f) {
  const uint32_t u = __float_as_uint(f);
  return (unsigned short)((u + 0x7FFFu + ((u >> 16) & 1u)) >> 16);
}

// Batched 6-value block reduction for BT=256 (4 waves): 36 shuffles, 2 syncs.
__device__ __forceinline__ void block_sum6(float p[NW], float* red /*[4*NW]*/) {
  #pragma unroll
  for (int w = 0; w < NW; ++w)
    #pragma unroll
    for (int off = 32; off > 0; off >>= 1) p[w] += __shfl_down(p[w], off, 64);
  const int t = threadIdx.x;
  __syncthreads();                       // protect red from previous use
  if ((t & 63) == 0) {
    #pragma unroll
    for (int w = 0; w < NW; ++w) red[(t >> 6) * NW + w] = p[w];
  }
  __syncthreads();
  #pragma unroll
  for (int w = 0; w < NW; ++w)
    p[w] = red[w] + red[NW + w] + red[2 * NW + w] + red[3 * NW + w];
}

// single-value block reduce for 256-thread trailing noise kernel
__device__ __forceinline__ float block_sum4(float v, float* red) {
  #pragma unroll
  for (int off = 32; off > 0; off >>= 1) v += __shfl_down(v, off, 64);
  const int t = threadIdx.x;
  __syncthreads();
  if ((t & 63) == 0) red[t >> 6] = v;
  __syncthreads();
  return red[0] + red[1] + red[2] + red[3];
}

__global__ void init_kernel(Flags* f, float* curve) {
  const int t = threadIdx.x;
  if (t == 0) {
    f->done = 0; f->apply_noise = 0;
    f->cnt_low = 0; f->cnt_high = 0; f->arrived = 0; f->sum_T = 0.0f;
  }
  if (t < NSTEPS) curve[t] = __int_as_float(0x7FC00000);   // NaN
}

// M[h][d][e] = sum_r U[h][d][r] * V[h][r][e], bf16 (hi only) in B-fragment
// order: frag = ((h*8 + nt)*4 + ks)*64 + lane, 8 bf16 each;
// lane = (e&15) | ((d>>3)&3)<<4, j = d&7, nt = e>>4, ks = d>>5.
__global__ __launch_bounds__(128) void precompute_M(const float* __restrict__ U,
                                                    const float* __restrict__ V,
                                                    unsigned short* __restrict__ Mhi) {
  const int hd = blockIdx.x;          // h*128 + d
  const int h = hd >> 7;
  const int d = hd & 127;
  const int e = threadIdx.x;
  __shared__ float u[64];
  if (e < 64) u[e] = U[hd * 64 + e];
  __syncthreads();
  float acc = 0.0f;
  #pragma unroll
  for (int r = 0; r < 64; ++r)
    acc = fmaf(u[r], V[(h * 64 + r) * 128 + e], acc);
  const int nt = e >> 4, ks = d >> 5;
  const int lane = (e & 15) | (((d >> 3) & 3) << 4);
  const int j = d & 7;
  const size_t idx = ((((size_t)(h * 8 + nt)) * 4 + ks) * 64 + lane) * 8 + j;
  Mhi[idx] = f2bf(acc);
}

// Slim fused per-step kernel: pending noise + MFMA drift (bf16-hi M,
// in-place into xs) + Euler + clamp_norm + tension; last-block ticket
// updates the global flags. LDS ~27.4 KB -> 5 blocks/CU.
__global__ __launch_bounds__(BT, 5) void step_kernel(
    const float* __restrict__ Sin, float* __restrict__ Sout,
    const float* __restrict__ signal,
    const unsigned short* __restrict__ Mhi,
    Flags* __restrict__ flags, float* __restrict__ curve,
    const int step_k, const uint32_t nk0, const uint32_t nk1,
    const int has_noise) {
  if (flags->done) return;
  __shared__ __align__(16) float xs[NW][NDP];    // 24.1 KB: x, then drift in-place
  __shared__ __align__(16) float mh[NW][NDH];    // 3 KB
  __shared__ float red[4 * NW];
  const int t = threadIdx.x;
  const int b = blockIdx.x;
  const int e0 = t << 2;              // 4 cols per thread (elementwise phases)

  // ---- phase 1: load rows, apply pending noise, stage to LDS, keep x in regs
  float v[NW][4];
  #pragma unroll
  for (int w = 0; w < NW; ++w) {
    const float4 a = *reinterpret_cast<const float4*>(
        Sin + (size_t)(b * NW + w) * ND + e0);
    v[w][0]=a.x; v[w][1]=a.y; v[w][2]=a.z; v[w][3]=a.w;
  }
  if (has_noise && flags->apply_noise) {
    float p[NW];
    #pragma unroll
    for (int w = 0; w < NW; ++w) {
      const uint32_t rowbase = (uint32_t)(b * NW + w) * ND + (uint32_t)e0;
      #pragma unroll
      for (int j = 0; j < 4; ++j)
        v[w][j] = fmaf(0.01f, noise_z(nk0, nk1, rowbase + (uint32_t)j), v[w][j]);
      p[w] = v[w][0]*v[w][0] + v[w][1]*v[w][1] + v[w][2]*v[w][2] + v[w][3]*v[w][3];
    }
    block_sum6(p, red);
    #pragma unroll
    for (int w = 0; w < NW; ++w) {
      const float inv = 1.0f / (sqrtf(p[w]) + 1e-8f);
      #pragma unroll
      for (int j = 0; j < 4; ++j) v[w][j] *= inv;
    }
  }
  #pragma unroll
  for (int w = 0; w < NW; ++w) {
    float4 a; a.x=v[w][0]; a.y=v[w][1]; a.z=v[w][2]; a.w=v[w][3];
    *reinterpret_cast<float4*>(&xs[w][e0]) = a;
  }
  __syncthreads();

  // ---- phase 2: cross-head mean (coupling) ----
  for (int idx = t; idx < NW * NDH; idx += BT) {   // 3 iters
    const int w = idx >> 7, el = idx & 127;
    float s = 0.0f;
    #pragma unroll
    for (int hh = 0; hh < NH; ++hh) s += xs[w][hh * NDH + el];
    mh[w][el] = s * 0.125f;
  }
  __syncthreads();

  // ---- phase 3: drift via MFMA (bf16-hi M), written in-place into xs ----
  // wave wv owns heads 2wv,2wv+1 (exclusive column ranges -> race-free).
  {
    const int l = t & 63, wv = t >> 6;
    const int arow = l & 15, kg = l >> 4;
    #pragma unroll 1
    for (int h2 = 0; h2 < 2; ++h2) {
      const int hh = wv * 2 + h2;
      f32x4 acc0,acc1,acc2,acc3,acc4,acc5,acc6,acc7;
      acc0=acc1=acc2=acc3=acc4=acc5=acc6=acc7=(f32x4){0.f,0.f,0.f,0.f};
      f32x4* accp[8] = {&acc0,&acc1,&acc2,&acc3,&acc4,&acc5,&acc6,&acc7};
      #pragma unroll
      for (int ks = 0; ks < 4; ++ks) {
        short8v ahi = (short8v)0;
        if (arow < NW) {
          const float* xp = &xs[arow][hh * NDH + ks * 32 + kg * 8];
          const float4 xa = *reinterpret_cast<const float4*>(xp);
          const float4 xb = *reinterpret_cast<const float4*>(xp + 4);
          const float xf[8] = {xa.x,xa.y,xa.z,xa.w,xb.x,xb.y,xb.z,xb.w};
          #pragma unroll
          for (int j = 0; j < 8; ++j) ahi[j] = (short)f2bf(xf[j]);
        }
        #pragma unroll
        for (int nt = 0; nt < 8; ++nt) {
          const size_t fo = ((((size_t)(hh * 8 + nt)) * 4 + ks) * 64 + l) * 8;
          const short8v bhi = *reinterpret_cast<const short8v*>(Mhi + fo);
          *accp[nt] = __builtin_amdgcn_mfma_f32_16x16x32_bf16(ahi, bhi, *accp[nt], 0, 0, 0);
        }
      }
      // scatter drift in-place (own-head columns only; all A-reads done)
      #pragma unroll
      for (int nt = 0; nt < 8; ++nt) {
        const f32x4 a = *accp[nt];
        #pragma unroll
        for (int r = 0; r < 4; ++r) {
          const int row = kg * 4 + r;
          if (row < NW) xs[row][hh * NDH + nt * 16 + arow] = a[r];
        }
      }
    }
  }
  __syncthreads();

  // ---- phase 4: Euler step (x from regs, drift from xs) ----
  float acc[NW][4];
  float p[NW];
  #pragma unroll
  for (int w = 0; w < NW; ++w) {
    const float4 sg = *reinterpret_cast<const float4*>(
        signal + (size_t)(b * NW + w) * ND + e0);
    const float4 dv = *reinterpret_cast<const float4*>(&xs[w][e0]);
    const float4 hh = *reinterpret_cast<const float4*>(&mh[w][e0 & 127]);
    const float sgf[4] = {sg.x, sg.y, sg.z, sg.w};
    const float dvf[4] = {dv.x, dv.y, dv.z, dv.w};
    const float mhf[4] = {hh.x, hh.y, hh.z, hh.w};
    float s2 = 0.0f;
    #pragma unroll
    for (int j = 0; j < 4; ++j) {
      const float out = -dvf[j] + C_COUP * (mhf[j] - v[w][j]) + sgf[j];
      acc[w][j] = fmaf(C_DT, out, v[w][j]);
      s2 = fmaf(acc[w][j], acc[w][j], s2);
    }
    p[w] = s2;
  }

  // ---- phase 5: clamp_norm (batched), write Sn, keep normed in regs ----
  block_sum6(p, red);
  #pragma unroll
  for (int w = 0; w < NW; ++w) {
    const float n = sqrtf(p[w]);
    const float scale = fminf(fmaxf(n, 1e-3f), 12.0f) / fmaxf(n, 1e-8f);
    const float inv_norm = 1.0f / (n * scale + 1e-12f);
    float4 o;
    o.x = acc[w][0]*scale; o.y = acc[w][1]*scale;
    o.z = acc[w][2]*scale; o.w = acc[w][3]*scale;
    *reinterpret_cast<float4*>(Sout + (size_t)(b * NW + w) * ND + e0) = o;
    acc[w][0]=o.x*inv_norm; acc[w][1]=o.y*inv_norm;
    acc[w][2]=o.z*inv_norm; acc[w][3]=o.w*inv_norm;
  }

  // ---- phase 6: tension from register-resident normed cols ----
  float pc[NW];
  #pragma unroll
  for (int w = 0; w < NW; ++w) pc[w] = 0.0f;
  #pragma unroll
  for (int j = 0; j < 4; ++j) {
    float md = 0.0f;
    #pragma unroll
    for (int w = 0; w < NW; ++w) md += acc[w][j];
    md *= (1.0f / 6.0f);
    #pragma unroll
    for (int w = 0; w < NW; ++w) pc[w] = fmaf(acc[w][j], md, pc[w]);
  }
  block_sum6(pc, red);

  if (t == 0) {
    const float cos_sum = pc[0]+pc[1]+pc[2]+pc[3]+pc[4]+pc[5];
    const float T = 1.0f - cos_sum * (1.0f / 6.0f);
    atomicAdd(&flags->sum_T, T);
    if (T < C_TOL)   atomicAdd(&flags->cnt_low, 1);
    if (T > C_THIGH) atomicAdd(&flags->cnt_high, 1);
    __threadfence();
    const int ticket = atomicAdd(&flags->arrived, 1);
    if (ticket == NB - 1) {
      const float sT = atomicAdd(&flags->sum_T, 0.0f);
      const int cl = atomicAdd(&flags->cnt_low, 0);
      const int ch = atomicAdd(&flags->cnt_high, 0);
      curve[step_k] = sT * (1.0f / 2048.0f);
      const int nd = (cl == NB) ? 1 : 0;
      flags->apply_noise = (!nd && ch > 0) ? 1 : 0;
      flags->done = nd;
      flags->sum_T = 0.0f; flags->cnt_low = 0; flags->cnt_high = 0;
      flags->arrived = 0;
      __threadfence();
    }
  }
}

// trailing noise for the final step (pending noise not consumed by a next step)
__global__ __launch_bounds__(256) void noise_kernel(float* __restrict__ S,
                                                    const Flags* __restrict__ flags,
                                                    const uint32_t k0, const uint32_t k1) {
  if (!flags->apply_noise) return;
  __shared__ float red[4];
  const int t = threadIdx.x;
  const uint32_t base = (uint32_t)blockIdx.x * ND + (t << 2);
  const float4 s = *reinterpret_cast<const float4*>(S + base);
  float v[4] = {s.x, s.y, s.z, s.w};
  #pragma unroll
  for (int j = 0; j < 4; ++j)
    v[j] = fmaf(0.01f, noise_z(k0, k1, base + (uint32_t)j), v[j]);
  const float p2 = v[0]*v[0] + v[1]*v[1] + v[2]*v[2] + v[3]*v[3];
  const float n2 = block_sum4(p2, red);
  const float inv = 1.0f / (sqrtf(n2) + 1e-8f);
  float4 o;
  o.x = v[0]*inv; o.y = v[1]*inv; o.z = v[2]*inv; o.w = v[3]*inv;
  *reinterpret_cast<float4*>(S + base) = o;
}

extern "C" void kernel_launch(void* const* d_in, const int* in_sizes, int n_in,
                              void* d_out, int out_size, void* d_ws, size_t ws_size,
                              hipStream_t stream) {
  const float* S0     = (const float*)d_in[0];
  const float* signal = (const float*)d_in[1];
  const float* U      = (const float*)d_in[2];
  const float* V      = (const float*)d_in[3];
  float* out   = (float*)d_out;
  float* curve = out + NTOT;
  Flags* flags = (Flags*)d_ws;
  unsigned short* Mhi = (unsigned short*)((char*)d_ws + 512);   // 256 KB

  init_kernel<<<1, 32, 0, stream>>>(flags, curve);
  precompute_M<<<NH * NDH, 128, 0, stream>>>(U, V, Mhi);

  // fold_in(key(1), k) for k=0..15 on host: threefry((0,1), (0,k))
  uint32_t K0[NSTEPS], K1[NSTEPS];
  for (uint32_t k = 0; k < NSTEPS; ++k) tf2x32(0u, 1u, 0u, k, K0[k], K1[k]);

  for (int k = 0; k < NSTEPS; ++k) {
    // step k consumes the pending noise of step k-1 (key K[k-1])
    step_kernel<<<NB, BT, 0, stream>>>(
        k == 0 ? S0 : out, out, signal, Mhi, flags, curve, k,
        k > 0 ? K0[k - 1] : 0u, k > 0 ? K1[k - 1] : 0u, k > 0 ? 1 : 0);
  }
  noise_kernel<<<NB * NW, 256, 0, stream>>>(out, flags, K0[NSTEPS - 1], K1[NSTEPS - 1]);
}

// Round 10
// 1575.330 us; speedup vs baseline: 2.3144x; 1.3967x over previous
//
#include <hip/hip_runtime.h>
#include <stdint.h>

#define NB 2048
#define NW 6
#define ND 1024
#define NH 8
#define NDH 128
#define NDP 1028          // padded LDS row stride (floats)
#define NTOT 12582912u
#define BT 256            // threads per step-kernel block (4 waves)
#define C_DT 0.09f
#define C_COUP 0.01f
#define C_TOL 0.05f
#define C_THIGH 0.22f
#define NSTEPS 16

typedef __attribute__((ext_vector_type(8))) short short8v;   // 8 bf16 (4 VGPR)
typedef __attribute__((ext_vector_type(4))) float f32x4;     // MFMA acc

struct Flags {
  int done; int apply_noise;
};

__host__ __device__ __forceinline__ uint32_t rotl32(uint32_t x, uint32_t d) {
  return (x << d) | (x >> (32u - d));
}

// JAX threefry2x32 (20 rounds), matches jax/_src/prng.py
__host__ __device__ __forceinline__ void tf2x32(uint32_t k0, uint32_t k1,
                                                uint32_t x0, uint32_t x1,
                                                uint32_t& o0, uint32_t& o1) {
  const uint32_t k2 = k0 ^ k1 ^ 0x1BD11BDAu;
#define TF_R4(a,b,c,d) \
  x0 += x1; x1 = rotl32(x1,a); x1 ^= x0; \
  x0 += x1; x1 = rotl32(x1,b); x1 ^= x0; \
  x0 += x1; x1 = rotl32(x1,c); x1 ^= x0; \
  x0 += x1; x1 = rotl32(x1,d); x1 ^= x0;
  x0 += k0; x1 += k1;
  TF_R4(13u,15u,26u,6u)  x0 += k1; x1 += k2 + 1u;
  TF_R4(17u,29u,16u,24u) x0 += k2; x1 += k0 + 2u;
  TF_R4(13u,15u,26u,6u)  x0 += k0; x1 += k1 + 3u;
  TF_R4(17u,29u,16u,24u) x0 += k1; x1 += k2 + 4u;
  TF_R4(13u,15u,26u,6u)  x0 += k2; x1 += k0 + 5u;
#undef TF_R4
  o0 = x0; o1 = x1;
}

// XLA ErfInv32 (Giles) polynomial — matches xla/client/lib/math.cc
__device__ __forceinline__ float erfinv_xla(float x) {
  const float w = -log1pf(-x * x);
  float ps, pb;
  const float ws = w - 2.5f;
  ps = 2.81022636e-08f;
  ps = fmaf(ps, ws, 3.43273939e-07f);
  ps = fmaf(ps, ws, -3.5233877e-06f);
  ps = fmaf(ps, ws, -4.39150654e-06f);
  ps = fmaf(ps, ws, 0.00021858087f);
  ps = fmaf(ps, ws, -0.00125372503f);
  ps = fmaf(ps, ws, -0.00417768164f);
  ps = fmaf(ps, ws, 0.246640727f);
  ps = fmaf(ps, ws, 1.50140941f);
  const float wb = sqrtf(w) - 3.0f;
  pb = -0.000200214257f;
  pb = fmaf(pb, wb, 0.000100950558f);
  pb = fmaf(pb, wb, 0.00134934322f);
  pb = fmaf(pb, wb, -0.00367342844f);
  pb = fmaf(pb, wb, 0.00573950773f);
  pb = fmaf(pb, wb, -0.0076224613f);
  pb = fmaf(pb, wb, 0.00943887047f);
  pb = fmaf(pb, wb, 1.00167406f);
  pb = fmaf(pb, wb, 2.83297682f);
  const float p = (w < 5.0f) ? ps : pb;
  return p * x;
}

__device__ __forceinline__ float noise_z(uint32_t k0, uint32_t k1, uint32_t p) {
  // JAX threefry_partitionable: counter (hi=0, lo=p), bits = o0 ^ o1
  uint32_t o0, o1;
  tf2x32(k0, k1, 0u, p, o0, o1);
  const uint32_t bits = o0 ^ o1;
  const float f = __uint_as_float((bits >> 9) | 0x3F800000u) - 1.0f;
  const float lo = -0.99999994f;                 // nextafter(-1,0) in f32
  const float u = fmaxf(lo, fmaf(f, 2.0f, lo));
  return 1.41421356237f * erfinv_xla(u);
}

// f32 -> bf16 round-to-nearest-even
__device__ __forceinline__ unsigned short f2bf(float f) {
  const uint32_t u = __float_as_uint(f);
  return (unsigned short)((u + 0x7FFFu + ((u >> 16) & 1u)) >> 16);
}

// Batched 6-value block reduction for BT=256 (4 waves): 36 shuffles, 2 syncs.
__device__ __forceinline__ void block_sum6(float p[NW], float* red /*[4*NW]*/) {
  #pragma unroll
  for (int w = 0; w < NW; ++w)
    #pragma unroll
    for (int off = 32; off > 0; off >>= 1) p[w] += __shfl_down(p[w], off, 64);
  const int t = threadIdx.x;
  __syncthreads();                       // protect red from previous use
  if ((t & 63) == 0) {
    #pragma unroll
    for (int w = 0; w < NW; ++w) red[(t >> 6) * NW + w] = p[w];
  }
  __syncthreads();
  #pragma unroll
  for (int w = 0; w < NW; ++w)
    p[w] = red[w] + red[NW + w] + red[2 * NW + w] + red[3 * NW + w];
}

// single-value block reduce for 256-thread trailing noise kernel
__device__ __forceinline__ float block_sum4(float v, float* red) {
  #pragma unroll
  for (int off = 32; off > 0; off >>= 1) v += __shfl_down(v, off, 64);
  const int t = threadIdx.x;
  __syncthreads();
  if ((t & 63) == 0) red[t >> 6] = v;
  __syncthreads();
  return red[0] + red[1] + red[2] + red[3];
}

__global__ void init_kernel(Flags* f, float* curve) {
  const int t = threadIdx.x;
  if (t == 0) { f->done = 0; f->apply_noise = 0; }
  if (t < NSTEPS) curve[t] = __int_as_float(0x7FC00000);   // NaN
}

// M[h][d][e] = sum_r U[h][d][r] * V[h][r][e], bf16 (hi only) in B-fragment
// order: frag = ((h*8 + nt)*4 + ks)*64 + lane, 8 bf16 each;
// lane = (e&15) | ((d>>3)&3)<<4, j = d&7, nt = e>>4, ks = d>>5.
__global__ __launch_bounds__(128) void precompute_M(const float* __restrict__ U,
                                                    const float* __restrict__ V,
                                                    unsigned short* __restrict__ Mhi) {
  const int hd = blockIdx.x;          // h*128 + d
  const int h = hd >> 7;
  const int d = hd & 127;
  const int e = threadIdx.x;
  __shared__ float u[64];
  if (e < 64) u[e] = U[hd * 64 + e];
  __syncthreads();
  float acc = 0.0f;
  #pragma unroll
  for (int r = 0; r < 64; ++r)
    acc = fmaf(u[r], V[(h * 64 + r) * 128 + e], acc);
  const int nt = e >> 4, ks = d >> 5;
  const int lane = (e & 15) | (((d >> 3) & 3) << 4);
  const int j = d & 7;
  const size_t idx = ((((size_t)(h * 8 + nt)) * 4 + ks) * 64 + lane) * 8 + j;
  Mhi[idx] = f2bf(acc);
}

// Slim fused per-step kernel. NO atomics: t0 stores T to Tarr[b]; a tiny
// flags_kernel between steps reduces and publishes done/apply/curve
// (cross-dispatch coherence — same guarantee that carries Sout -> Sin).
// Signal is prefetched in phase 1 (doubles outstanding loads; removes the
// phase-4 latency stall).
__global__ __launch_bounds__(BT, 5) void step_kernel(
    const float* __restrict__ Sin, float* __restrict__ Sout,
    const float* __restrict__ signal,
    const unsigned short* __restrict__ Mhi,
    const Flags* __restrict__ flags, float* __restrict__ Tarr,
    const uint32_t nk0, const uint32_t nk1, const int has_noise) {
  if (flags->done) return;
  __shared__ __align__(16) float xs[NW][NDP];    // 24.1 KB: x, then drift in-place
  __shared__ __align__(16) float mh[NW][NDH];    // 3 KB
  __shared__ float red[4 * NW];
  const int t = threadIdx.x;
  const int b = blockIdx.x;
  const int e0 = t << 2;              // 4 cols per thread (elementwise phases)

  // ---- phase 1: issue Sin AND signal loads together (max MLP) ----
  float v[NW][4];
  float sg[NW][4];
  #pragma unroll
  for (int w = 0; w < NW; ++w) {
    const float4 a = *reinterpret_cast<const float4*>(
        Sin + (size_t)(b * NW + w) * ND + e0);
    v[w][0]=a.x; v[w][1]=a.y; v[w][2]=a.z; v[w][3]=a.w;
  }
  #pragma unroll
  for (int w = 0; w < NW; ++w) {
    const float4 a = *reinterpret_cast<const float4*>(
        signal + (size_t)(b * NW + w) * ND + e0);
    sg[w][0]=a.x; sg[w][1]=a.y; sg[w][2]=a.z; sg[w][3]=a.w;
  }
  if (has_noise && flags->apply_noise) {
    float p[NW];
    #pragma unroll
    for (int w = 0; w < NW; ++w) {
      const uint32_t rowbase = (uint32_t)(b * NW + w) * ND + (uint32_t)e0;
      #pragma unroll
      for (int j = 0; j < 4; ++j)
        v[w][j] = fmaf(0.01f, noise_z(nk0, nk1, rowbase + (uint32_t)j), v[w][j]);
      p[w] = v[w][0]*v[w][0] + v[w][1]*v[w][1] + v[w][2]*v[w][2] + v[w][3]*v[w][3];
    }
    block_sum6(p, red);
    #pragma unroll
    for (int w = 0; w < NW; ++w) {
      const float inv = 1.0f / (sqrtf(p[w]) + 1e-8f);
      #pragma unroll
      for (int j = 0; j < 4; ++j) v[w][j] *= inv;
    }
  }
  #pragma unroll
  for (int w = 0; w < NW; ++w) {
    float4 a; a.x=v[w][0]; a.y=v[w][1]; a.z=v[w][2]; a.w=v[w][3];
    *reinterpret_cast<float4*>(&xs[w][e0]) = a;
  }
  __syncthreads();

  // ---- phase 2: cross-head mean (coupling) ----
  for (int idx = t; idx < NW * NDH; idx += BT) {   // 3 iters
    const int w = idx >> 7, el = idx & 127;
    float s = 0.0f;
    #pragma unroll
    for (int hh = 0; hh < NH; ++hh) s += xs[w][hh * NDH + el];
    mh[w][el] = s * 0.125f;
  }
  __syncthreads();

  // ---- phase 3: drift via MFMA (bf16-hi M), written in-place into xs ----
  // wave wv owns heads 2wv,2wv+1 (exclusive column ranges -> race-free).
  {
    const int l = t & 63, wv = t >> 6;
    const int arow = l & 15, kg = l >> 4;
    #pragma unroll 1
    for (int h2 = 0; h2 < 2; ++h2) {
      const int hh = wv * 2 + h2;
      f32x4 acc0,acc1,acc2,acc3,acc4,acc5,acc6,acc7;
      acc0=acc1=acc2=acc3=acc4=acc5=acc6=acc7=(f32x4){0.f,0.f,0.f,0.f};
      f32x4* accp[8] = {&acc0,&acc1,&acc2,&acc3,&acc4,&acc5,&acc6,&acc7};
      #pragma unroll
      for (int ks = 0; ks < 4; ++ks) {
        short8v ahi = (short8v)0;
        if (arow < NW) {
          const float* xp = &xs[arow][hh * NDH + ks * 32 + kg * 8];
          const float4 xa = *reinterpret_cast<const float4*>(xp);
          const float4 xb = *reinterpret_cast<const float4*>(xp + 4);
          const float xf[8] = {xa.x,xa.y,xa.z,xa.w,xb.x,xb.y,xb.z,xb.w};
          #pragma unroll
          for (int j = 0; j < 8; ++j) ahi[j] = (short)f2bf(xf[j]);
        }
        #pragma unroll
        for (int nt = 0; nt < 8; ++nt) {
          const size_t fo = ((((size_t)(hh * 8 + nt)) * 4 + ks) * 64 + l) * 8;
          const short8v bhi = *reinterpret_cast<const short8v*>(Mhi + fo);
          *accp[nt] = __builtin_amdgcn_mfma_f32_16x16x32_bf16(ahi, bhi, *accp[nt], 0, 0, 0);
        }
      }
      // scatter drift in-place (own-head columns only; all A-reads done)
      #pragma unroll
      for (int nt = 0; nt < 8; ++nt) {
        const f32x4 a = *accp[nt];
        #pragma unroll
        for (int r = 0; r < 4; ++r) {
          const int row = kg * 4 + r;
          if (row < NW) xs[row][hh * NDH + nt * 16 + arow] = a[r];
        }
      }
    }
  }
  __syncthreads();

  // ---- phase 4: Euler step (x, signal from regs; drift from xs) ----
  float acc[NW][4];
  float p[NW];
  #pragma unroll
  for (int w = 0; w < NW; ++w) {
    const float4 dv = *reinterpret_cast<const float4*>(&xs[w][e0]);
    const float4 hh = *reinterpret_cast<const float4*>(&mh[w][e0 & 127]);
    const float dvf[4] = {dv.x, dv.y, dv.z, dv.w};
    const float mhf[4] = {hh.x, hh.y, hh.z, hh.w};
    float s2 = 0.0f;
    #pragma unroll
    for (int j = 0; j < 4; ++j) {
      const float out = -dvf[j] + C_COUP * (mhf[j] - v[w][j]) + sg[w][j];
      acc[w][j] = fmaf(C_DT, out, v[w][j]);
      s2 = fmaf(acc[w][j], acc[w][j], s2);
    }
    p[w] = s2;
  }

  // ---- phase 5: clamp_norm (batched), write Sn, keep normed in regs ----
  block_sum6(p, red);
  #pragma unroll
  for (int w = 0; w < NW; ++w) {
    const float n = sqrtf(p[w]);
    const float scale = fminf(fmaxf(n, 1e-3f), 12.0f) / fmaxf(n, 1e-8f);
    const float inv_norm = 1.0f / (n * scale + 1e-12f);
    float4 o;
    o.x = acc[w][0]*scale; o.y = acc[w][1]*scale;
    o.z = acc[w][2]*scale; o.w = acc[w][3]*scale;
    *reinterpret_cast<float4*>(Sout + (size_t)(b * NW + w) * ND + e0) = o;
    acc[w][0]=o.x*inv_norm; acc[w][1]=o.y*inv_norm;
    acc[w][2]=o.z*inv_norm; acc[w][3]=o.w*inv_norm;
  }

  // ---- phase 6: tension from register-resident normed cols ----
  float pc[NW];
  #pragma unroll
  for (int w = 0; w < NW; ++w) pc[w] = 0.0f;
  #pragma unroll
  for (int j = 0; j < 4; ++j) {
    float md = 0.0f;
    #pragma unroll
    for (int w = 0; w < NW; ++w) md += acc[w][j];
    md *= (1.0f / 6.0f);
    #pragma unroll
    for (int w = 0; w < NW; ++w) pc[w] = fmaf(acc[w][j], md, pc[w]);
  }
  block_sum6(pc, red);

  if (t == 0) {
    const float cos_sum = pc[0]+pc[1]+pc[2]+pc[3]+pc[4]+pc[5];
    Tarr[b] = 1.0f - cos_sum * (1.0f / 6.0f);     // plain store, no contention
  }
}

// 1-block reduction of Tarr -> flags + curve[k] (replaces all atomics)
__global__ __launch_bounds__(256) void flags_kernel(
    Flags* __restrict__ f, const float* __restrict__ Tarr,
    float* __restrict__ curve, const int step_k) {
  __shared__ float red[12];
  const int t = threadIdx.x;
  const int done_old = f->done;
  float s = 0.0f, cl = 0.0f, ch = 0.0f;
  for (int i = t; i < NB; i += 256) {
    const float T = Tarr[i];
    s += T;
    cl += (T < C_TOL) ? 1.0f : 0.0f;
    ch += (T > C_THIGH) ? 1.0f : 0.0f;
  }
  #pragma unroll
  for (int off = 32; off > 0; off >>= 1) {
    s  += __shfl_down(s,  off, 64);
    cl += __shfl_down(cl, off, 64);
    ch += __shfl_down(ch, off, 64);
  }
  if ((t & 63) == 0) {
    red[(t >> 6) * 3 + 0] = s;
    red[(t >> 6) * 3 + 1] = cl;
    red[(t >> 6) * 3 + 2] = ch;
  }
  __syncthreads();
  if (t == 0) {
    const float sT  = red[0] + red[3] + red[6] + red[9];
    const float cln = red[1] + red[4] + red[7] + red[10];
    const float chn = red[2] + red[5] + red[8] + red[11];
    curve[step_k] = done_old ? __int_as_float(0x7FC00000) : sT * (1.0f / 2048.0f);
    const int nd = (done_old || cln == (float)NB) ? 1 : 0;
    f->apply_noise = (!nd && chn > 0.0f) ? 1 : 0;
    f->done = nd;
  }
}

// trailing noise for the final step (pending noise not consumed by a next step)
__global__ __launch_bounds__(256) void noise_kernel(float* __restrict__ S,
                                                    const Flags* __restrict__ flags,
                                                    const uint32_t k0, const uint32_t k1) {
  if (!flags->apply_noise) return;
  __shared__ float red[4];
  const int t = threadIdx.x;
  const uint32_t base = (uint32_t)blockIdx.x * ND + (t << 2);
  const float4 s = *reinterpret_cast<const float4*>(S + base);
  float v[4] = {s.x, s.y, s.z, s.w};
  #pragma unroll
  for (int j = 0; j < 4; ++j)
    v[j] = fmaf(0.01f, noise_z(k0, k1, base + (uint32_t)j), v[j]);
  const float p2 = v[0]*v[0] + v[1]*v[1] + v[2]*v[2] + v[3]*v[3];
  const float n2 = block_sum4(p2, red);
  const float inv = 1.0f / (sqrtf(n2) + 1e-8f);
  float4 o;
  o.x = v[0]*inv; o.y = v[1]*inv; o.z = v[2]*inv; o.w = v[3]*inv;
  *reinterpret_cast<float4*>(S + base) = o;
}

extern "C" void kernel_launch(void* const* d_in, const int* in_sizes, int n_in,
                              void* d_out, int out_size, void* d_ws, size_t ws_size,
                              hipStream_t stream) {
  const float* S0     = (const float*)d_in[0];
  const float* signal = (const float*)d_in[1];
  const float* U      = (const float*)d_in[2];
  const float* V      = (const float*)d_in[3];
  float* out   = (float*)d_out;
  float* curve = out + NTOT;
  Flags* flags = (Flags*)d_ws;
  float* Tarr  = (float*)((char*)d_ws + 512);                  // 8 KB
  unsigned short* Mhi = (unsigned short*)((char*)d_ws + 16384); // 256 KB

  init_kernel<<<1, 32, 0, stream>>>(flags, curve);
  precompute_M<<<NH * NDH, 128, 0, stream>>>(U, V, Mhi);

  // fold_in(key(1), k) for k=0..15 on host: threefry((0,1), (0,k))
  uint32_t K0[NSTEPS], K1[NSTEPS];
  for (uint32_t k = 0; k < NSTEPS; ++k) tf2x32(0u, 1u, 0u, k, K0[k], K1[k]);

  for (int k = 0; k < NSTEPS; ++k) {
    // step k consumes the pending noise of step k-1 (key K[k-1])
    step_kernel<<<NB, BT, 0, stream>>>(
        k == 0 ? S0 : out, out, signal, Mhi, flags, Tarr,
        k > 0 ? K0[k - 1] : 0u, k > 0 ? K1[k - 1] : 0u, k > 0 ? 1 : 0);
    flags_kernel<<<1, 256, 0, stream>>>(flags, Tarr, curve, k);
  }
  noise_kernel<<<NB * NW, 256, 0, stream>>>(out, flags, K0[NSTEPS - 1], K1[NSTEPS - 1]);
}

// Round 11
// 1093.462 us; speedup vs baseline: 3.3343x; 1.4407x over previous
//
#include <hip/hip_runtime.h>
#include <stdint.h>

#define NB 2048
#define NW 6
#define ND 1024
#define NH 8
#define NDH 128
#define NDP 1028          // padded LDS row stride (floats)
#define NTOT 12582912u
#define BT 256            // threads per step-kernel block (4 waves)
#define C_DT 0.09f
#define C_COUP 0.01f
#define C_TOL 0.05f
#define C_THIGH 0.22f
#define NSTEPS 16

typedef __attribute__((ext_vector_type(8))) short short8v;   // 8 bf16 (4 VGPR)
typedef __attribute__((ext_vector_type(4))) float f32x4;     // MFMA acc

struct Flags {
  int done; int apply_noise;
};

__host__ __device__ __forceinline__ uint32_t rotl32(uint32_t x, uint32_t d) {
  return (x << d) | (x >> (32u - d));
}

// JAX threefry2x32 (20 rounds), matches jax/_src/prng.py
__host__ __device__ __forceinline__ void tf2x32(uint32_t k0, uint32_t k1,
                                                uint32_t x0, uint32_t x1,
                                                uint32_t& o0, uint32_t& o1) {
  const uint32_t k2 = k0 ^ k1 ^ 0x1BD11BDAu;
#define TF_R4(a,b,c,d) \
  x0 += x1; x1 = rotl32(x1,a); x1 ^= x0; \
  x0 += x1; x1 = rotl32(x1,b); x1 ^= x0; \
  x0 += x1; x1 = rotl32(x1,c); x1 ^= x0; \
  x0 += x1; x1 = rotl32(x1,d); x1 ^= x0;
  x0 += k0; x1 += k1;
  TF_R4(13u,15u,26u,6u)  x0 += k1; x1 += k2 + 1u;
  TF_R4(17u,29u,16u,24u) x0 += k2; x1 += k0 + 2u;
  TF_R4(13u,15u,26u,6u)  x0 += k0; x1 += k1 + 3u;
  TF_R4(17u,29u,16u,24u) x0 += k1; x1 += k2 + 4u;
  TF_R4(13u,15u,26u,6u)  x0 += k2; x1 += k0 + 5u;
#undef TF_R4
  o0 = x0; o1 = x1;
}

// XLA ErfInv32 (Giles) coefficients; w via fast hardware log (v_log_f32).
// log1p(-x^2) -> logf(1-x^2): abs error ~1e-7 on the argument, z error
// <3e-5 except ~1e-6-probability tail elements (~3e-4 noise error there) —
// all far below the 1.66e-2 threshold. pb branch taken per wave only when
// any lane has w>=5 (P ~ 1.3%).
__device__ __forceinline__ float erfinv_fast(float x) {
  const float w = -__logf(fmaf(x, -x, 1.0f));
  const float ws = w - 2.5f;
  float ps = 2.81022636e-08f;
  ps = fmaf(ps, ws, 3.43273939e-07f);
  ps = fmaf(ps, ws, -3.5233877e-06f);
  ps = fmaf(ps, ws, -4.39150654e-06f);
  ps = fmaf(ps, ws, 0.00021858087f);
  ps = fmaf(ps, ws, -0.00125372503f);
  ps = fmaf(ps, ws, -0.00417768164f);
  ps = fmaf(ps, ws, 0.246640727f);
  ps = fmaf(ps, ws, 1.50140941f);
  if (__any(w >= 5.0f)) {                     // rare tail: full Giles big-branch
    const float wb = sqrtf(w) - 3.0f;
    float pb = -0.000200214257f;
    pb = fmaf(pb, wb, 0.000100950558f);
    pb = fmaf(pb, wb, 0.00134934322f);
    pb = fmaf(pb, wb, -0.00367342844f);
    pb = fmaf(pb, wb, 0.00573950773f);
    pb = fmaf(pb, wb, -0.0076224613f);
    pb = fmaf(pb, wb, 0.00943887047f);
    pb = fmaf(pb, wb, 1.00167406f);
    pb = fmaf(pb, wb, 2.83297682f);
    return ((w < 5.0f) ? ps : pb) * x;
  }
  return ps * x;
}

__device__ __forceinline__ float noise_z(uint32_t k0, uint32_t k1, uint32_t p) {
  // JAX threefry_partitionable: counter (hi=0, lo=p), bits = o0 ^ o1
  uint32_t o0, o1;
  tf2x32(k0, k1, 0u, p, o0, o1);
  const uint32_t bits = o0 ^ o1;
  const float f = __uint_as_float((bits >> 9) | 0x3F800000u) - 1.0f;
  const float lo = -0.99999994f;                 // nextafter(-1,0) in f32
  const float u = fmaxf(lo, fmaf(f, 2.0f, lo));
  return 1.41421356237f * erfinv_fast(u);
}

// f32 -> bf16 round-to-nearest-even
__device__ __forceinline__ unsigned short f2bf(float f) {
  const uint32_t u = __float_as_uint(f);
  return (unsigned short)((u + 0x7FFFu + ((u >> 16) & 1u)) >> 16);
}

// Batched 6-value block reduction for BT=256 (4 waves): 36 shuffles, 2 syncs.
__device__ __forceinline__ void block_sum6(float p[NW], float* red /*[4*NW]*/) {
  #pragma unroll
  for (int w = 0; w < NW; ++w)
    #pragma unroll
    for (int off = 32; off > 0; off >>= 1) p[w] += __shfl_down(p[w], off, 64);
  const int t = threadIdx.x;
  __syncthreads();                       // protect red from previous use
  if ((t & 63) == 0) {
    #pragma unroll
    for (int w = 0; w < NW; ++w) red[(t >> 6) * NW + w] = p[w];
  }
  __syncthreads();
  #pragma unroll
  for (int w = 0; w < NW; ++w)
    p[w] = red[w] + red[NW + w] + red[2 * NW + w] + red[3 * NW + w];
}

// single-value block reduce for 256-thread trailing noise kernel
__device__ __forceinline__ float block_sum4(float v, float* red) {
  #pragma unroll
  for (int off = 32; off > 0; off >>= 1) v += __shfl_down(v, off, 64);
  const int t = threadIdx.x;
  __syncthreads();
  if ((t & 63) == 0) red[t >> 6] = v;
  __syncthreads();
  return red[0] + red[1] + red[2] + red[3];
}

__global__ void init_kernel(Flags* f, float* curve) {
  const int t = threadIdx.x;
  if (t == 0) { f->done = 0; f->apply_noise = 0; }
  if (t < NSTEPS) curve[t] = __int_as_float(0x7FC00000);   // NaN
}

// M[h][d][e] = sum_r U[h][d][r] * V[h][r][e], bf16 (hi only) in B-fragment
// order: frag = ((h*8 + nt)*4 + ks)*64 + lane, 8 bf16 each;
// lane = (e&15) | ((d>>3)&3)<<4, j = d&7, nt = e>>4, ks = d>>5.
__global__ __launch_bounds__(128) void precompute_M(const float* __restrict__ U,
                                                    const float* __restrict__ V,
                                                    unsigned short* __restrict__ Mhi) {
  const int hd = blockIdx.x;          // h*128 + d
  const int h = hd >> 7;
  const int d = hd & 127;
  const int e = threadIdx.x;
  __shared__ float u[64];
  if (e < 64) u[e] = U[hd * 64 + e];
  __syncthreads();
  float acc = 0.0f;
  #pragma unroll
  for (int r = 0; r < 64; ++r)
    acc = fmaf(u[r], V[(h * 64 + r) * 128 + e], acc);
  const int nt = e >> 4, ks = d >> 5;
  const int lane = (e & 15) | (((d >> 3) & 3) << 4);
  const int j = d & 7;
  const size_t idx = ((((size_t)(h * 8 + nt)) * 4 + ks) * 64 + lane) * 8 + j;
  Mhi[idx] = f2bf(acc);
}

// Slim fused per-step kernel (no atomics, signal prefetched).
// __launch_bounds__(BT,4): ~128-VGPR budget so v/sg/acc stay in registers
// (the (BT,5) build chose 48 VGPRs and spilled ~72 B/thread to scratch —
// visible as WRITE_SIZE 86 MB vs 48 MB of real output).
__global__ __launch_bounds__(BT, 4) void step_kernel(
    const float* __restrict__ Sin, float* __restrict__ Sout,
    const float* __restrict__ signal,
    const unsigned short* __restrict__ Mhi,
    const Flags* __restrict__ flags, float* __restrict__ Tarr,
    const uint32_t nk0, const uint32_t nk1, const int has_noise) {
  if (flags->done) return;
  __shared__ __align__(16) float xs[NW][NDP];    // 24.1 KB: x, then drift in-place
  __shared__ __align__(16) float mh[NW][NDH];    // 3 KB
  __shared__ float red[4 * NW];
  const int t = threadIdx.x;
  const int b = blockIdx.x;
  const int e0 = t << 2;              // 4 cols per thread (elementwise phases)

  // ---- phase 1: issue Sin AND signal loads together (max MLP) ----
  float v[NW][4];
  float sg[NW][4];
  #pragma unroll
  for (int w = 0; w < NW; ++w) {
    const float4 a = *reinterpret_cast<const float4*>(
        Sin + (size_t)(b * NW + w) * ND + e0);
    v[w][0]=a.x; v[w][1]=a.y; v[w][2]=a.z; v[w][3]=a.w;
  }
  #pragma unroll
  for (int w = 0; w < NW; ++w) {
    const float4 a = *reinterpret_cast<const float4*>(
        signal + (size_t)(b * NW + w) * ND + e0);
    sg[w][0]=a.x; sg[w][1]=a.y; sg[w][2]=a.z; sg[w][3]=a.w;
  }
  if (has_noise && flags->apply_noise) {
    float p[NW];
    #pragma unroll
    for (int w = 0; w < NW; ++w) {
      const uint32_t rowbase = (uint32_t)(b * NW + w) * ND + (uint32_t)e0;
      #pragma unroll
      for (int j = 0; j < 4; ++j)
        v[w][j] = fmaf(0.01f, noise_z(nk0, nk1, rowbase + (uint32_t)j), v[w][j]);
      p[w] = v[w][0]*v[w][0] + v[w][1]*v[w][1] + v[w][2]*v[w][2] + v[w][3]*v[w][3];
    }
    block_sum6(p, red);
    #pragma unroll
    for (int w = 0; w < NW; ++w) {
      const float inv = 1.0f / (sqrtf(p[w]) + 1e-8f);
      #pragma unroll
      for (int j = 0; j < 4; ++j) v[w][j] *= inv;
    }
  }
  #pragma unroll
  for (int w = 0; w < NW; ++w) {
    float4 a; a.x=v[w][0]; a.y=v[w][1]; a.z=v[w][2]; a.w=v[w][3];
    *reinterpret_cast<float4*>(&xs[w][e0]) = a;
  }
  __syncthreads();

  // ---- phase 2: cross-head mean (coupling) ----
  for (int idx = t; idx < NW * NDH; idx += BT) {   // 3 iters
    const int w = idx >> 7, el = idx & 127;
    float s = 0.0f;
    #pragma unroll
    for (int hh = 0; hh < NH; ++hh) s += xs[w][hh * NDH + el];
    mh[w][el] = s * 0.125f;
  }
  __syncthreads();

  // ---- phase 3: drift via MFMA (bf16-hi M), written in-place into xs ----
  // wave wv owns heads 2wv,2wv+1 (exclusive column ranges -> race-free).
  {
    const int l = t & 63, wv = t >> 6;
    const int arow = l & 15, kg = l >> 4;
    #pragma unroll 1
    for (int h2 = 0; h2 < 2; ++h2) {
      const int hh = wv * 2 + h2;
      f32x4 acc0,acc1,acc2,acc3,acc4,acc5,acc6,acc7;
      acc0=acc1=acc2=acc3=acc4=acc5=acc6=acc7=(f32x4){0.f,0.f,0.f,0.f};
      f32x4* accp[8] = {&acc0,&acc1,&acc2,&acc3,&acc4,&acc5,&acc6,&acc7};
      #pragma unroll
      for (int ks = 0; ks < 4; ++ks) {
        short8v ahi = (short8v)0;
        if (arow < NW) {
          const float* xp = &xs[arow][hh * NDH + ks * 32 + kg * 8];
          const float4 xa = *reinterpret_cast<const float4*>(xp);
          const float4 xb = *reinterpret_cast<const float4*>(xp + 4);
          const float xf[8] = {xa.x,xa.y,xa.z,xa.w,xb.x,xb.y,xb.z,xb.w};
          #pragma unroll
          for (int j = 0; j < 8; ++j) ahi[j] = (short)f2bf(xf[j]);
        }
        #pragma unroll
        for (int nt = 0; nt < 8; ++nt) {
          const size_t fo = ((((size_t)(hh * 8 + nt)) * 4 + ks) * 64 + l) * 8;
          const short8v bhi = *reinterpret_cast<const short8v*>(Mhi + fo);
          *accp[nt] = __builtin_amdgcn_mfma_f32_16x16x32_bf16(ahi, bhi, *accp[nt], 0, 0, 0);
        }
      }
      // scatter drift in-place (own-head columns only; all A-reads done)
      #pragma unroll
      for (int nt = 0; nt < 8; ++nt) {
        const f32x4 a = *accp[nt];
        #pragma unroll
        for (int r = 0; r < 4; ++r) {
          const int row = kg * 4 + r;
          if (row < NW) xs[row][hh * NDH + nt * 16 + arow] = a[r];
        }
      }
    }
  }
  __syncthreads();

  // ---- phase 4: Euler step (x, signal from regs; drift from xs) ----
  float acc[NW][4];
  float p[NW];
  #pragma unroll
  for (int w = 0; w < NW; ++w) {
    const float4 dv = *reinterpret_cast<const float4*>(&xs[w][e0]);
    const float4 hh = *reinterpret_cast<const float4*>(&mh[w][e0 & 127]);
    const float dvf[4] = {dv.x, dv.y, dv.z, dv.w};
    const float mhf[4] = {hh.x, hh.y, hh.z, hh.w};
    float s2 = 0.0f;
    #pragma unroll
    for (int j = 0; j < 4; ++j) {
      const float out = -dvf[j] + C_COUP * (mhf[j] - v[w][j]) + sg[w][j];
      acc[w][j] = fmaf(C_DT, out, v[w][j]);
      s2 = fmaf(acc[w][j], acc[w][j], s2);
    }
    p[w] = s2;
  }

  // ---- phase 5: clamp_norm (batched), write Sn, keep normed in regs ----
  block_sum6(p, red);
  #pragma unroll
  for (int w = 0; w < NW; ++w) {
    const float n = sqrtf(p[w]);
    const float scale = fminf(fmaxf(n, 1e-3f), 12.0f) / fmaxf(n, 1e-8f);
    const float inv_norm = 1.0f / (n * scale + 1e-12f);
    float4 o;
    o.x = acc[w][0]*scale; o.y = acc[w][1]*scale;
    o.z = acc[w][2]*scale; o.w = acc[w][3]*scale;
    *reinterpret_cast<float4*>(Sout + (size_t)(b * NW + w) * ND + e0) = o;
    acc[w][0]=o.x*inv_norm; acc[w][1]=o.y*inv_norm;
    acc[w][2]=o.z*inv_norm; acc[w][3]=o.w*inv_norm;
  }

  // ---- phase 6: tension from register-resident normed cols ----
  float pc[NW];
  #pragma unroll
  for (int w = 0; w < NW; ++w) pc[w] = 0.0f;
  #pragma unroll
  for (int j = 0; j < 4; ++j) {
    float md = 0.0f;
    #pragma unroll
    for (int w = 0; w < NW; ++w) md += acc[w][j];
    md *= (1.0f / 6.0f);
    #pragma unroll
    for (int w = 0; w < NW; ++w) pc[w] = fmaf(acc[w][j], md, pc[w]);
  }
  block_sum6(pc, red);

  if (t == 0) {
    const float cos_sum = pc[0]+pc[1]+pc[2]+pc[3]+pc[4]+pc[5];
    Tarr[b] = 1.0f - cos_sum * (1.0f / 6.0f);     // plain store, no contention
  }
}

// 1-block reduction of Tarr -> flags + curve[k] (replaces all atomics)
__global__ __launch_bounds__(256) void flags_kernel(
    Flags* __restrict__ f, const float* __restrict__ Tarr,
    float* __restrict__ curve, const int step_k) {
  __shared__ float red[12];
  const int t = threadIdx.x;
  const int done_old = f->done;
  float s = 0.0f, cl = 0.0f, ch = 0.0f;
  for (int i = t; i < NB; i += 256) {
    const float T = Tarr[i];
    s += T;
    cl += (T < C_TOL) ? 1.0f : 0.0f;
    ch += (T > C_THIGH) ? 1.0f : 0.0f;
  }
  #pragma unroll
  for (int off = 32; off > 0; off >>= 1) {
    s  += __shfl_down(s,  off, 64);
    cl += __shfl_down(cl, off, 64);
    ch += __shfl_down(ch, off, 64);
  }
  if ((t & 63) == 0) {
    red[(t >> 6) * 3 + 0] = s;
    red[(t >> 6) * 3 + 1] = cl;
    red[(t >> 6) * 3 + 2] = ch;
  }
  __syncthreads();
  if (t == 0) {
    const float sT  = red[0] + red[3] + red[6] + red[9];
    const float cln = red[1] + red[4] + red[7] + red[10];
    const float chn = red[2] + red[5] + red[8] + red[11];
    curve[step_k] = done_old ? __int_as_float(0x7FC00000) : sT * (1.0f / 2048.0f);
    const int nd = (done_old || cln == (float)NB) ? 1 : 0;
    f->apply_noise = (!nd && chn > 0.0f) ? 1 : 0;
    f->done = nd;
  }
}

// trailing noise for the final step (pending noise not consumed by a next step)
__global__ __launch_bounds__(256) void noise_kernel(float* __restrict__ S,
                                                    const Flags* __restrict__ flags,
                                                    const uint32_t k0, const uint32_t k1) {
  if (!flags->apply_noise) return;
  __shared__ float red[4];
  const int t = threadIdx.x;
  const uint32_t base = (uint32_t)blockIdx.x * ND + (t << 2);
  const float4 s = *reinterpret_cast<const float4*>(S + base);
  float v[4] = {s.x, s.y, s.z, s.w};
  #pragma unroll
  for (int j = 0; j < 4; ++j)
    v[j] = fmaf(0.01f, noise_z(k0, k1, base + (uint32_t)j), v[j]);
  const float p2 = v[0]*v[0] + v[1]*v[1] + v[2]*v[2] + v[3]*v[3];
  const float n2 = block_sum4(p2, red);
  const float inv = 1.0f / (sqrtf(n2) + 1e-8f);
  float4 o;
  o.x = v[0]*inv; o.y = v[1]*inv; o.z = v[2]*inv; o.w = v[3]*inv;
  *reinterpret_cast<float4*>(S + base) = o;
}

extern "C" void kernel_launch(void* const* d_in, const int* in_sizes, int n_in,
                              void* d_out, int out_size, void* d_ws, size_t ws_size,
                              hipStream_t stream) {
  const float* S0     = (const float*)d_in[0];
  const float* signal = (const float*)d_in[1];
  const float* U      = (const float*)d_in[2];
  const float* V      = (const float*)d_in[3];
  float* out   = (float*)d_out;
  float* curve = out + NTOT;
  Flags* flags = (Flags*)d_ws;
  float* Tarr  = (float*)((char*)d_ws + 512);                  // 8 KB
  unsigned short* Mhi = (unsigned short*)((char*)d_ws + 16384); // 256 KB

  init_kernel<<<1, 32, 0, stream>>>(flags, curve);
  precompute_M<<<NH * NDH, 128, 0, stream>>>(U, V, Mhi);

  // fold_in(key(1), k) for k=0..15 on host: threefry((0,1), (0,k))
  uint32_t K0[NSTEPS], K1[NSTEPS];
  for (uint32_t k = 0; k < NSTEPS; ++k) tf2x32(0u, 1u, 0u, k, K0[k], K1[k]);

  for (int k = 0; k < NSTEPS; ++k) {
    // step k consumes the pending noise of step k-1 (key K[k-1])
    step_kernel<<<NB, BT, 0, stream>>>(
        k == 0 ? S0 : out, out, signal, Mhi, flags, Tarr,
        k > 0 ? K0[k - 1] : 0u, k > 0 ? K1[k - 1] : 0u, k > 0 ? 1 : 0);
    flags_kernel<<<1, 256, 0, stream>>>(flags, Tarr, curve, k);
  }
  noise_kernel<<<NB * NW, 256, 0, stream>>>(out, flags, K0[NSTEPS - 1], K1[NSTEPS - 1]);
}